// Round 5
// baseline (825.890 us; speedup 1.0000x reference)
//
#include <hip/hip_runtime.h>

#define NSAMP 4096
#define KCH   128
#define MDIM  7

typedef __attribute__((ext_vector_type(8))) short bf16x8;
typedef __attribute__((ext_vector_type(4))) float f32x4;

static constexpr int RB[4] = {0, 1, 4, 9};
static constexpr int RE[4] = {1, 4, 9, 16};
static constexpr int PR_L[16] = {0,1,1,1,2,2,2,2,2,3,3,3,3,3,3,3};
static constexpr int PR_M[16] = {0,0,1,2,0,1,2,3,4,0,1,2,3,4,5,6};

// CG paths in Python enumeration order
static constexpr int P_L1[34] = {0,1,2,3, 0,1,1,1,2,2,2,3,3, 0,1,1,1,2,2,2,2,3,3,3, 0,1,1,2,2,2,3,3,3,3};
static constexpr int P_L2[34] = {0,1,2,3, 1,0,1,2,1,2,3,2,3, 2,1,2,3,0,1,2,3,1,2,3, 3,2,3,1,2,3,0,1,2,3};
static constexpr int P_LO[34] = {0,0,0,0, 1,1,1,1,1,1,1,1,1, 2,2,2,2,2,2,2,2,2,2,2, 3,3,3,3,3,3,3,3,3,3};

// invalid (l,m) rows for zero-fill
static constexpr int ZL[12] = {0,0,0,0,0,0, 1,1,1,1, 2,2};
static constexpr int ZM[12] = {1,2,3,4,5,6, 3,4,5,6, 5,6};

#define WP_BYTES 1310720u   // 1280 sets * 512 shorts * 2B

static __device__ __forceinline__ unsigned short f2bf(float x) {
    unsigned u = __builtin_bit_cast(unsigned, x);
    u = u + 0x7FFFu + ((u >> 16) & 1u);
    return (unsigned short)(u >> 16);
}
static __device__ __forceinline__ float bf2f(unsigned short h) {
    unsigned u = ((unsigned)h) << 16;
    return __builtin_bit_cast(float, u);
}

// ---------------- K0: W -> bf16 hi/lo in B-fragment order ----------------
__global__ __launch_bounds__(256) void cg_prep(const float* __restrict__ mW,
                                               const float* __restrict__ iW,
                                               unsigned short* __restrict__ Wp)
{
    int gid = blockIdx.x * 256 + threadIdx.x;
    int lane = gid & 63;
    int set  = gid >> 6;                            // 1280 sets
    int spl = set & 1;
    int ks  = (set >> 1) & 3;
    int ct  = (set >> 3) & 7;
    int l   = (set >> 6) & 3;
    int mi  = set >> 8;                             // 0..4
    const float* src = (mi < 3) ? (mW + ((size_t)mi * 4 + l) * (KCH * KCH))
                                : (iW + ((size_t)(mi - 3) * 4 + l) * (KCH * KCH));
    int j  = ct * 16 + (lane & 15);
    int kb = ks * 32 + (lane >> 4) * 8;
    unsigned short o[8];
#pragma unroll
    for (int e = 0; e < 8; ++e) {
        float w = src[(size_t)(kb + e) * KCH + j];
        unsigned short h = f2bf(w);
        o[e] = spl ? f2bf(w - bf2f(h)) : h;
    }
    uint4 pk;
    unsigned* pw = (unsigned*)&pk;
#pragma unroll
    for (int q = 0; q < 4; ++q) pw[q] = (unsigned)o[2*q] | ((unsigned)o[2*q+1] << 16);
    *(uint4*)(Wp + (size_t)set * 512 + lane * 8) = pk;
}

// A-fragment read from bf16 plane [256 rows][128], chunk-XOR swizzled by (key&7)
static __device__ __forceinline__ bf16x8 ldF(const unsigned short* P, int row16, int key, int c) {
    int cs = c ^ (key & 7);
    return *(const bf16x8*)(P + row16 * 128 + cs * 8);
}

// ---------------- K2: three mixer GEMMs, rows = samples ----------------
__global__ __launch_bounds__(512, 2) void cg_mix3(const float* __restrict__ feats,
                                                  const bf16x8* __restrict__ Wp,
                                                  float* __restrict__ P0,
                                                  float* __restrict__ P1,
                                                  float* __restrict__ P2,
                                                  int base)
{
    extern __shared__ char smem[];
    unsigned short* Fh = (unsigned short*)smem;            // 64 KB: [256 rows][128]
    unsigned short* Fl = Fh + 32768;                       // 64 KB

    const int tid  = threadIdx.x;
    const int lane = tid & 63;
    const int ct   = tid >> 6;              // wave id = j col-tile
    const int nl0  = blockIdx.x * 16;       // chunk-local sample base

    // ---- stage feats -> hi/lo bf16 LDS, rows (r,n), XOR-swizzled chunks ----
    {
        const int row = tid >> 1;           // 0..255 = r*16 + nlr
        const int r   = row >> 4;
        const int nlr = row & 15;
        const int kh  = tid & 1;
        const int l = PR_L[r], m = PR_M[r];
        const float* g = feats + (((size_t)l * NSAMP + (base + nl0 + nlr)) * MDIM + m) * KCH + kh * 64;
        unsigned short* fh = Fh + row * 128;
        unsigned short* fl = Fl + row * 128;
#pragma unroll
        for (int c8 = 0; c8 < 8; ++c8) {
            f32x4 a = *(const f32x4*)(g + c8 * 8);
            f32x4 b = *(const f32x4*)(g + c8 * 8 + 4);
            float v[8] = {a[0], a[1], a[2], a[3], b[0], b[1], b[2], b[3]};
            unsigned short hi[8], lo[8];
#pragma unroll
            for (int i = 0; i < 8; ++i) {
                hi[i] = f2bf(v[i]);
                lo[i] = f2bf(v[i] - bf2f(hi[i]));
            }
            uint4 ph, pl;
            unsigned* pwh = (unsigned*)&ph;
            unsigned* pwl = (unsigned*)&pl;
#pragma unroll
            for (int q = 0; q < 4; ++q) {
                pwh[q] = (unsigned)hi[2*q] | ((unsigned)hi[2*q+1] << 16);
                pwl[q] = (unsigned)lo[2*q] | ((unsigned)lo[2*q+1] << 16);
            }
            const int cs = (kh * 8 + c8) ^ (nlr & 7);
            *(uint4*)(fh + cs * 8) = ph;
            *(uint4*)(fl + cs * 8) = pl;
        }
    }
    __syncthreads();

    const int kg = lane >> 4;
    const int l15 = lane & 15;
    const int j = ct * 16 + l15;

    // ---- dual sweep: mi = 0 and 1 ----
    f32x4 acc0[16], acc1[16];
#pragma unroll
    for (int r = 0; r < 16; ++r) {
        acc0[r][0]=acc0[r][1]=acc0[r][2]=acc0[r][3]=0.0f;
        acc1[r][0]=acc1[r][1]=acc1[r][2]=acc1[r][3]=0.0f;
    }
#pragma unroll
    for (int ks = 0; ks < 4; ++ks) {
#pragma unroll
        for (int l = 0; l < 4; ++l) {
            const int s0 = (((0 * 4 + l) * 8 + ct) * 4 + ks) * 2;
            const int s1 = (((1 * 4 + l) * 8 + ct) * 4 + ks) * 2;
            bf16x8 b0h = Wp[(size_t)s0 * 64 + lane];
            bf16x8 b0l = Wp[(size_t)(s0 + 1) * 64 + lane];
            bf16x8 b1h = Wp[(size_t)s1 * 64 + lane];
            bf16x8 b1l = Wp[(size_t)(s1 + 1) * 64 + lane];
#pragma unroll
            for (int r = RB[l]; r < RE[l]; ++r) {
                bf16x8 ah = ldF(Fh, r * 16 + l15, l15, ks * 4 + kg);
                bf16x8 al = ldF(Fl, r * 16 + l15, l15, ks * 4 + kg);
                acc0[r] = __builtin_amdgcn_mfma_f32_16x16x32_bf16(ah, b0h, acc0[r], 0, 0, 0);
                acc0[r] = __builtin_amdgcn_mfma_f32_16x16x32_bf16(ah, b0l, acc0[r], 0, 0, 0);
                acc0[r] = __builtin_amdgcn_mfma_f32_16x16x32_bf16(al, b0h, acc0[r], 0, 0, 0);
                acc1[r] = __builtin_amdgcn_mfma_f32_16x16x32_bf16(ah, b1h, acc1[r], 0, 0, 0);
                acc1[r] = __builtin_amdgcn_mfma_f32_16x16x32_bf16(ah, b1l, acc1[r], 0, 0, 0);
                acc1[r] = __builtin_amdgcn_mfma_f32_16x16x32_bf16(al, b1h, acc1[r], 0, 0, 0);
            }
        }
    }
#pragma unroll
    for (int r = 0; r < 16; ++r) {
#pragma unroll
        for (int q = 0; q < 4; ++q) {
            const int nl = nl0 + (lane >> 4) * 4 + q;
            P0[((size_t)nl * 16 + r) * KCH + j] = acc0[r][q];
            P1[((size_t)nl * 16 + r) * KCH + j] = acc1[r][q];
        }
    }

    // ---- single sweep: mi = 2 ----
#pragma unroll
    for (int r = 0; r < 16; ++r) { acc0[r][0]=acc0[r][1]=acc0[r][2]=acc0[r][3]=0.0f; }
#pragma unroll
    for (int ks = 0; ks < 4; ++ks) {
#pragma unroll
        for (int l = 0; l < 4; ++l) {
            const int s0 = (((2 * 4 + l) * 8 + ct) * 4 + ks) * 2;
            bf16x8 bh = Wp[(size_t)s0 * 64 + lane];
            bf16x8 bl = Wp[(size_t)(s0 + 1) * 64 + lane];
#pragma unroll
            for (int r = RB[l]; r < RE[l]; ++r) {
                bf16x8 ah = ldF(Fh, r * 16 + l15, l15, ks * 4 + kg);
                bf16x8 al = ldF(Fl, r * 16 + l15, l15, ks * 4 + kg);
                acc0[r] = __builtin_amdgcn_mfma_f32_16x16x32_bf16(ah, bh, acc0[r], 0, 0, 0);
                acc0[r] = __builtin_amdgcn_mfma_f32_16x16x32_bf16(ah, bl, acc0[r], 0, 0, 0);
                acc0[r] = __builtin_amdgcn_mfma_f32_16x16x32_bf16(al, bh, acc0[r], 0, 0, 0);
            }
        }
    }
#pragma unroll
    for (int r = 0; r < 16; ++r) {
#pragma unroll
        for (int q = 0; q < 4; ++q) {
            const int nl = nl0 + (lane >> 4) * 4 + q;
            P2[((size_t)nl * 16 + r) * KCH + j] = acc0[r][q];
        }
    }
}

// ---------------- K3: fused TP + iter mix + residual ----------------
// Phase 1: per-thread TP (2 channels x 2 tasks) -> hi/lo bf16 into swizzled LDS
// Phase 2: MFMA sweep, acc initialized from residual Pc, store.
template<int T>
__global__ __launch_bounds__(512, 2) void cg_fiter(const float* __restrict__ Pc,
                                                   const float* __restrict__ Pm,
                                                   const float* __restrict__ Uc,
                                                   const bf16x8* __restrict__ Wp,
                                                   float* __restrict__ Pout,
                                                   float* __restrict__ gout,
                                                   int base)
{
    extern __shared__ char smem[];
    unsigned short* Th = (unsigned short*)smem;   // 64 KB: [256 rows][128]
    unsigned short* Tl = Th + 32768;              // 64 KB

    const int tid  = threadIdx.x;
    const int lane = tid & 63;
    const int ct   = tid >> 6;
    const int nl0  = blockIdx.x * 16;

    // ---- phase 1: tensor product, 2 tasks x 2 channels per thread ----
#pragma unroll
    for (int it = 0; it < 2; ++it) {
        const int task = it * 512 + tid;        // 0..1023
        const int nl   = task >> 6;             // 0..15
        const int ch   = (task & 63) * 2;       // even channel
        const float* pc = Pc + ((size_t)(nl0 + nl) * 16) * KCH + ch;
        const float* pm = Pm + ((size_t)(nl0 + nl) * 16) * KCH + ch;

        float cv[16][2], mv[16][2], tv[16][2];
#pragma unroll
        for (int r = 0; r < 16; ++r) {
            const float2 a = *(const float2*)(pc + r * KCH);
            const float2 b = *(const float2*)(pm + r * KCH);
            cv[r][0] = a.x; cv[r][1] = a.y;
            mv[r][0] = b.x; mv[r][1] = b.y;
            tv[r][0] = 0.0f; tv[r][1] = 0.0f;
        }
#pragma unroll
        for (int p = 0; p < 34; ++p) {
            const int l1 = P_L1[p], l2 = P_L2[p], Lo = P_LO[p];
            const float* __restrict__ Up = Uc + p * 343;
#pragma unroll
            for (int a = 0; a < 2 * l1 + 1; ++a) {
#pragma unroll
                for (int b = 0; b < 2 * l2 + 1; ++b) {
                    const float p0 = cv[RB[l1] + a][0] * mv[RB[l2] + b][0];
                    const float p1 = cv[RB[l1] + a][1] * mv[RB[l2] + b][1];
#pragma unroll
                    for (int c = 0; c < 2 * Lo + 1; ++c) {
                        const float u = Up[(a * 7 + b) * 7 + c];
                        tv[RB[Lo] + c][0] += p0 * u;
                        tv[RB[Lo] + c][1] += p1 * u;
                    }
                }
            }
        }
        // write hi/lo planes, packed 2 channels per b32, swizzle key = nl&7
        const int off = (((ch >> 3) ^ (nl & 7)) << 3) + (ch & 7);
#pragma unroll
        for (int r = 0; r < 16; ++r) {
            const int row = nl * 16 + r;
            const unsigned short h0 = f2bf(tv[r][0]);
            const unsigned short h1 = f2bf(tv[r][1]);
            const unsigned short l0 = f2bf(tv[r][0] - bf2f(h0));
            const unsigned short l1 = f2bf(tv[r][1] - bf2f(h1));
            *(unsigned*)(Th + row * 128 + off) = (unsigned)h0 | ((unsigned)h1 << 16);
            *(unsigned*)(Tl + row * 128 + off) = (unsigned)l0 | ((unsigned)l1 << 16);
        }
    }
    __syncthreads();

    // ---- phase 2: MFMA sweep, acc initialized from residual ----
    const int kg = lane >> 4;
    const int l15 = lane & 15;
    const int j = ct * 16 + l15;

    f32x4 acc[16];
#pragma unroll
    for (int r = 0; r < 16; ++r) {
#pragma unroll
        for (int q = 0; q < 4; ++q) {
            const int nl = (lane >> 4) * 4 + q;
            acc[r][q] = Pc[((size_t)(nl0 + nl) * 16 + r) * KCH + j];
        }
    }

#pragma unroll
    for (int ks = 0; ks < 4; ++ks) {
#pragma unroll
        for (int l = 0; l < 4; ++l) {
            const int s0 = ((((3 + T) * 4 + l) * 8 + ct) * 4 + ks) * 2;
            bf16x8 bh = Wp[(size_t)s0 * 64 + lane];
            bf16x8 bl = Wp[(size_t)(s0 + 1) * 64 + lane];
#pragma unroll
            for (int r = RB[l]; r < RE[l]; ++r) {
                bf16x8 ah = ldF(Th, l15 * 16 + r, l15, ks * 4 + kg);
                bf16x8 al = ldF(Tl, l15 * 16 + r, l15, ks * 4 + kg);
                acc[r] = __builtin_amdgcn_mfma_f32_16x16x32_bf16(ah, bh, acc[r], 0, 0, 0);
                acc[r] = __builtin_amdgcn_mfma_f32_16x16x32_bf16(ah, bl, acc[r], 0, 0, 0);
                acc[r] = __builtin_amdgcn_mfma_f32_16x16x32_bf16(al, bh, acc[r], 0, 0, 0);
            }
        }
    }

#pragma unroll
    for (int r = 0; r < 16; ++r) {
#pragma unroll
        for (int q = 0; q < 4; ++q) {
            const int nl = nl0 + (lane >> 4) * 4 + q;
            const float val = acc[r][q];
            if (T == 0) {
                Pout[((size_t)nl * 16 + r) * KCH + j] = val;
            } else {
                const int n = base + nl;
                gout[(((size_t)PR_L[r] * NSAMP + n) * MDIM + PR_M[r]) * KCH + j] = val;
            }
        }
    }

    if (T == 1) {
        // zero-fill the 12 invalid (l,m) rows
        const int j2 = tid & 127;
        const int g  = tid >> 7;     // 0..3
#pragma unroll
        for (int z = 0; z < 12; ++z) {
#pragma unroll
            for (int i = 0; i < 4; ++i) {
                const int n = base + nl0 + g * 4 + i;
                gout[(((size_t)ZL[z] * NSAMP + n) * MDIM + ZM[z]) * KCH + j2] = 0.0f;
            }
        }
    }
}

extern "C" void kernel_launch(void* const* d_in, const int* in_sizes, int n_in,
                              void* d_out, int out_size, void* d_ws, size_t ws_size,
                              hipStream_t stream)
{
    const float* feats = (const float*)d_in[0];
    const float* U     = (const float*)d_in[1];
    const float* mW    = (const float*)d_in[2];
    const float* iW    = (const float*)d_in[3];
    float* out = (float*)d_out;

    // chunk size by workspace: per-sample = 3 * 16*128*4 B = 24576 B
    size_t avail = (ws_size > WP_BYTES) ? (ws_size - WP_BYTES) : 0;
    int NC = (int)(avail / 24576);
    NC = (NC / 16) * 16;
    if (NC > NSAMP) NC = NSAMP;
    if (NC < 16) return;   // workspace too small (not observed)

    char* wsb = (char*)d_ws;
    unsigned short* Wp = (unsigned short*)wsb;
    float* P0 = (float*)(wsb + WP_BYTES);
    float* P1 = P0 + (size_t)NC * 2048;
    float* P2 = P1 + (size_t)NC * 2048;

    hipFuncSetAttribute(reinterpret_cast<const void*>(cg_mix3),
                        hipFuncAttributeMaxDynamicSharedMemorySize, 131072);
    hipFuncSetAttribute(reinterpret_cast<const void*>(cg_fiter<0>),
                        hipFuncAttributeMaxDynamicSharedMemorySize, 131072);
    hipFuncSetAttribute(reinterpret_cast<const void*>(cg_fiter<1>),
                        hipFuncAttributeMaxDynamicSharedMemorySize, 131072);

    cg_prep<<<320, 256, 0, stream>>>(mW, iW, Wp);

    for (int base = 0; base < NSAMP; base += NC) {
        const int nc = (NSAMP - base < NC) ? (NSAMP - base) : NC;
        cg_mix3<<<nc / 16, 512, 131072, stream>>>(feats, (const bf16x8*)Wp, P0, P1, P2, base);
        // cur1 = P0 + mix(tp(P0,P1), iW0)  -> overwrite P1
        cg_fiter<0><<<nc / 16, 512, 131072, stream>>>(P0, P1, U, (const bf16x8*)Wp, P1, nullptr, base);
        // out  = P1 + mix(tp(P1,P2), iW1)
        cg_fiter<1><<<nc / 16, 512, 131072, stream>>>(P1, P2, U, (const bf16x8*)Wp, nullptr, out, base);
    }
}

// Round 6
// 737.887 us; speedup vs baseline: 1.1193x; 1.1193x over previous
//
#include <hip/hip_runtime.h>

#define NSAMP 4096
#define KCH   128
#define MDIM  7

typedef __attribute__((ext_vector_type(8))) short bf16x8;
typedef __attribute__((ext_vector_type(4))) float f32x4;

static constexpr int RB[4] = {0, 1, 4, 9};
static constexpr int RE[4] = {1, 4, 9, 16};
static constexpr int PR_L[16] = {0,1,1,1,2,2,2,2,2,3,3,3,3,3,3,3};
static constexpr int PR_M[16] = {0,0,1,2,0,1,2,3,4,0,1,2,3,4,5,6};

// CG paths in Python enumeration order
static constexpr int P_L1[34] = {0,1,2,3, 0,1,1,1,2,2,2,3,3, 0,1,1,1,2,2,2,2,3,3,3, 0,1,1,2,2,2,3,3,3,3};
static constexpr int P_L2[34] = {0,1,2,3, 1,0,1,2,1,2,3,2,3, 2,1,2,3,0,1,2,3,1,2,3, 3,2,3,1,2,3,0,1,2,3};
static constexpr int P_LO[34] = {0,0,0,0, 1,1,1,1,1,1,1,1,1, 2,2,2,2,2,2,2,2,2,2,2, 3,3,3,3,3,3,3,3,3,3};

// invalid (l,m) rows for zero-fill
static constexpr int ZL[12] = {0,0,0,0,0,0, 1,1,1,1, 2,2};
static constexpr int ZM[12] = {1,2,3,4,5,6, 3,4,5,6, 5,6};

#define WP_BYTES 1310720u   // 1280 sets * 512 shorts * 2B

static __device__ __forceinline__ unsigned short f2bf(float x) {
    unsigned u = __builtin_bit_cast(unsigned, x);
    u = u + 0x7FFFu + ((u >> 16) & 1u);
    return (unsigned short)(u >> 16);
}
static __device__ __forceinline__ float bf2f(unsigned short h) {
    unsigned u = ((unsigned)h) << 16;
    return __builtin_bit_cast(float, u);
}

// ---------------- K0: W -> bf16 hi/lo in B-fragment order ----------------
__global__ __launch_bounds__(256) void cg_prep(const float* __restrict__ mW,
                                               const float* __restrict__ iW,
                                               unsigned short* __restrict__ Wp)
{
    int gid = blockIdx.x * 256 + threadIdx.x;
    int lane = gid & 63;
    int set  = gid >> 6;                            // 1280 sets
    int spl = set & 1;
    int ks  = (set >> 1) & 3;
    int ct  = (set >> 3) & 7;
    int l   = (set >> 6) & 3;
    int mi  = set >> 8;                             // 0..4
    const float* src = (mi < 3) ? (mW + ((size_t)mi * 4 + l) * (KCH * KCH))
                                : (iW + ((size_t)(mi - 3) * 4 + l) * (KCH * KCH));
    int j  = ct * 16 + (lane & 15);
    int kb = ks * 32 + (lane >> 4) * 8;
    unsigned short o[8];
#pragma unroll
    for (int e = 0; e < 8; ++e) {
        float w = src[(size_t)(kb + e) * KCH + j];
        unsigned short h = f2bf(w);
        o[e] = spl ? f2bf(w - bf2f(h)) : h;
    }
    uint4 pk;
    unsigned* pw = (unsigned*)&pk;
#pragma unroll
    for (int q = 0; q < 4; ++q) pw[q] = (unsigned)o[2*q] | ((unsigned)o[2*q+1] << 16);
    *(uint4*)(Wp + (size_t)set * 512 + lane * 8) = pk;
}

// A-fragment read from bf16 plane [256 rows][128], chunk-XOR swizzled by (key&7)
static __device__ __forceinline__ bf16x8 ldF(const unsigned short* P, int row16, int key, int c) {
    int cs = c ^ (key & 7);
    return *(const bf16x8*)(P + row16 * 128 + cs * 8);
}

// ---------------- K2: three mixer GEMMs, rows = samples ----------------
__global__ __launch_bounds__(512, 1) void cg_mix3(const float* __restrict__ feats,
                                                  const bf16x8* __restrict__ Wp,
                                                  float* __restrict__ P0,
                                                  float* __restrict__ P1,
                                                  float* __restrict__ P2,
                                                  int base)
{
    extern __shared__ char smem[];
    unsigned short* Fh = (unsigned short*)smem;            // 64 KB: [256 rows][128]
    unsigned short* Fl = Fh + 32768;                       // 64 KB

    const int tid  = threadIdx.x;
    const int lane = tid & 63;
    const int ct   = tid >> 6;              // wave id = j col-tile
    const int nl0  = blockIdx.x * 16;       // chunk-local sample base

    // ---- stage feats -> hi/lo bf16 LDS, rows (r,n), XOR-swizzled chunks ----
    {
        const int row = tid >> 1;           // 0..255 = r*16 + nlr
        const int r   = row >> 4;
        const int nlr = row & 15;
        const int kh  = tid & 1;
        const int l = PR_L[r], m = PR_M[r];
        const float* g = feats + (((size_t)l * NSAMP + (base + nl0 + nlr)) * MDIM + m) * KCH + kh * 64;
        unsigned short* fh = Fh + row * 128;
        unsigned short* fl = Fl + row * 128;
#pragma unroll
        for (int c8 = 0; c8 < 8; ++c8) {
            f32x4 a = *(const f32x4*)(g + c8 * 8);
            f32x4 b = *(const f32x4*)(g + c8 * 8 + 4);
            float v[8] = {a[0], a[1], a[2], a[3], b[0], b[1], b[2], b[3]};
            unsigned short hi[8], lo[8];
#pragma unroll
            for (int i = 0; i < 8; ++i) {
                hi[i] = f2bf(v[i]);
                lo[i] = f2bf(v[i] - bf2f(hi[i]));
            }
            uint4 ph, pl;
            unsigned* pwh = (unsigned*)&ph;
            unsigned* pwl = (unsigned*)&pl;
#pragma unroll
            for (int q = 0; q < 4; ++q) {
                pwh[q] = (unsigned)hi[2*q] | ((unsigned)hi[2*q+1] << 16);
                pwl[q] = (unsigned)lo[2*q] | ((unsigned)lo[2*q+1] << 16);
            }
            const int cs = (kh * 8 + c8) ^ (nlr & 7);
            *(uint4*)(fh + cs * 8) = ph;
            *(uint4*)(fl + cs * 8) = pl;
        }
    }
    __syncthreads();

    const int kg = lane >> 4;
    const int l15 = lane & 15;
    const int j = ct * 16 + l15;

    // ---- dual sweep: mi = 0 and 1 ----
    f32x4 acc0[16], acc1[16];
#pragma unroll
    for (int r = 0; r < 16; ++r) {
        acc0[r][0]=acc0[r][1]=acc0[r][2]=acc0[r][3]=0.0f;
        acc1[r][0]=acc1[r][1]=acc1[r][2]=acc1[r][3]=0.0f;
    }
#pragma unroll
    for (int ks = 0; ks < 4; ++ks) {
#pragma unroll
        for (int l = 0; l < 4; ++l) {
            const int s0 = (((0 * 4 + l) * 8 + ct) * 4 + ks) * 2;
            const int s1 = (((1 * 4 + l) * 8 + ct) * 4 + ks) * 2;
            bf16x8 b0h = Wp[(size_t)s0 * 64 + lane];
            bf16x8 b0l = Wp[(size_t)(s0 + 1) * 64 + lane];
            bf16x8 b1h = Wp[(size_t)s1 * 64 + lane];
            bf16x8 b1l = Wp[(size_t)(s1 + 1) * 64 + lane];
#pragma unroll
            for (int r = RB[l]; r < RE[l]; ++r) {
                bf16x8 ah = ldF(Fh, r * 16 + l15, l15, ks * 4 + kg);
                bf16x8 al = ldF(Fl, r * 16 + l15, l15, ks * 4 + kg);
                acc0[r] = __builtin_amdgcn_mfma_f32_16x16x32_bf16(ah, b0h, acc0[r], 0, 0, 0);
                acc0[r] = __builtin_amdgcn_mfma_f32_16x16x32_bf16(ah, b0l, acc0[r], 0, 0, 0);
                acc0[r] = __builtin_amdgcn_mfma_f32_16x16x32_bf16(al, b0h, acc0[r], 0, 0, 0);
                acc1[r] = __builtin_amdgcn_mfma_f32_16x16x32_bf16(ah, b1h, acc1[r], 0, 0, 0);
                acc1[r] = __builtin_amdgcn_mfma_f32_16x16x32_bf16(ah, b1l, acc1[r], 0, 0, 0);
                acc1[r] = __builtin_amdgcn_mfma_f32_16x16x32_bf16(al, b1h, acc1[r], 0, 0, 0);
            }
        }
    }
#pragma unroll
    for (int r = 0; r < 16; ++r) {
#pragma unroll
        for (int q = 0; q < 4; ++q) {
            const int nl = nl0 + (lane >> 4) * 4 + q;
            P0[((size_t)nl * 16 + r) * KCH + j] = acc0[r][q];
            P1[((size_t)nl * 16 + r) * KCH + j] = acc1[r][q];
        }
    }

    // ---- single sweep: mi = 2 ----
#pragma unroll
    for (int r = 0; r < 16; ++r) { acc0[r][0]=acc0[r][1]=acc0[r][2]=acc0[r][3]=0.0f; }
#pragma unroll
    for (int ks = 0; ks < 4; ++ks) {
#pragma unroll
        for (int l = 0; l < 4; ++l) {
            const int s0 = (((2 * 4 + l) * 8 + ct) * 4 + ks) * 2;
            bf16x8 bh = Wp[(size_t)s0 * 64 + lane];
            bf16x8 bl = Wp[(size_t)(s0 + 1) * 64 + lane];
#pragma unroll
            for (int r = RB[l]; r < RE[l]; ++r) {
                bf16x8 ah = ldF(Fh, r * 16 + l15, l15, ks * 4 + kg);
                bf16x8 al = ldF(Fl, r * 16 + l15, l15, ks * 4 + kg);
                acc0[r] = __builtin_amdgcn_mfma_f32_16x16x32_bf16(ah, bh, acc0[r], 0, 0, 0);
                acc0[r] = __builtin_amdgcn_mfma_f32_16x16x32_bf16(ah, bl, acc0[r], 0, 0, 0);
                acc0[r] = __builtin_amdgcn_mfma_f32_16x16x32_bf16(al, bh, acc0[r], 0, 0, 0);
            }
        }
    }
#pragma unroll
    for (int r = 0; r < 16; ++r) {
#pragma unroll
        for (int q = 0; q < 4; ++q) {
            const int nl = nl0 + (lane >> 4) * 4 + q;
            P2[((size_t)nl * 16 + r) * KCH + j] = acc0[r][q];
        }
    }
}

// ---------------- K3: fused TP + iter mix + residual ----------------
// Phase 1: per-thread TP (2 channels x 2 tasks) -> hi/lo bf16 into swizzled LDS
// Phase 2: MFMA sweep, acc initialized from residual Pc, store.
template<int T>
__global__ __launch_bounds__(512, 1) void cg_fiter(const float* __restrict__ Pc,
                                                   const float* __restrict__ Pm,
                                                   const float* __restrict__ Uc,
                                                   const bf16x8* __restrict__ Wp,
                                                   float* __restrict__ Pout,
                                                   float* __restrict__ gout,
                                                   int base)
{
    extern __shared__ char smem[];
    unsigned short* Th = (unsigned short*)smem;   // 64 KB: [256 rows][128]
    unsigned short* Tl = Th + 32768;              // 64 KB

    const int tid  = threadIdx.x;
    const int lane = tid & 63;
    const int ct   = tid >> 6;
    const int nl0  = blockIdx.x * 16;

    // ---- phase 1: tensor product, 2 tasks x 2 channels per thread ----
#pragma unroll
    for (int it = 0; it < 2; ++it) {
        const int task = it * 512 + tid;        // 0..1023
        const int nl   = task >> 6;             // 0..15
        const int ch   = (task & 63) * 2;       // even channel
        const float* pc = Pc + ((size_t)(nl0 + nl) * 16) * KCH + ch;
        const float* pm = Pm + ((size_t)(nl0 + nl) * 16) * KCH + ch;

        float cv[16][2], mv[16][2], tv[16][2];
#pragma unroll
        for (int r = 0; r < 16; ++r) {
            const float2 a = *(const float2*)(pc + r * KCH);
            const float2 b = *(const float2*)(pm + r * KCH);
            cv[r][0] = a.x; cv[r][1] = a.y;
            mv[r][0] = b.x; mv[r][1] = b.y;
            tv[r][0] = 0.0f; tv[r][1] = 0.0f;
        }
#pragma unroll
        for (int p = 0; p < 34; ++p) {
            const int l1 = P_L1[p], l2 = P_L2[p], Lo = P_LO[p];
            const float* __restrict__ Up = Uc + p * 343;
#pragma unroll
            for (int a = 0; a < 2 * l1 + 1; ++a) {
#pragma unroll
                for (int b = 0; b < 2 * l2 + 1; ++b) {
                    const float p0 = cv[RB[l1] + a][0] * mv[RB[l2] + b][0];
                    const float p1 = cv[RB[l1] + a][1] * mv[RB[l2] + b][1];
#pragma unroll
                    for (int c = 0; c < 2 * Lo + 1; ++c) {
                        const float u = Up[(a * 7 + b) * 7 + c];
                        tv[RB[Lo] + c][0] += p0 * u;
                        tv[RB[Lo] + c][1] += p1 * u;
                    }
                }
            }
        }
        // write hi/lo planes, packed 2 channels per b32, swizzle key = nl&7
        const int off = (((ch >> 3) ^ (nl & 7)) << 3) + (ch & 7);
#pragma unroll
        for (int r = 0; r < 16; ++r) {
            const int row = nl * 16 + r;
            const unsigned short h0 = f2bf(tv[r][0]);
            const unsigned short h1 = f2bf(tv[r][1]);
            const unsigned short l0 = f2bf(tv[r][0] - bf2f(h0));
            const unsigned short l1 = f2bf(tv[r][1] - bf2f(h1));
            *(unsigned*)(Th + row * 128 + off) = (unsigned)h0 | ((unsigned)h1 << 16);
            *(unsigned*)(Tl + row * 128 + off) = (unsigned)l0 | ((unsigned)l1 << 16);
        }
    }
    __syncthreads();

    // ---- phase 2: MFMA sweep, acc initialized from residual ----
    const int kg = lane >> 4;
    const int l15 = lane & 15;
    const int j = ct * 16 + l15;

    f32x4 acc[16];
#pragma unroll
    for (int r = 0; r < 16; ++r) {
#pragma unroll
        for (int q = 0; q < 4; ++q) {
            const int nl = (lane >> 4) * 4 + q;
            acc[r][q] = Pc[((size_t)(nl0 + nl) * 16 + r) * KCH + j];
        }
    }

#pragma unroll
    for (int ks = 0; ks < 4; ++ks) {
#pragma unroll
        for (int l = 0; l < 4; ++l) {
            const int s0 = ((((3 + T) * 4 + l) * 8 + ct) * 4 + ks) * 2;
            bf16x8 bh = Wp[(size_t)s0 * 64 + lane];
            bf16x8 bl = Wp[(size_t)(s0 + 1) * 64 + lane];
#pragma unroll
            for (int r = RB[l]; r < RE[l]; ++r) {
                bf16x8 ah = ldF(Th, l15 * 16 + r, l15, ks * 4 + kg);
                bf16x8 al = ldF(Tl, l15 * 16 + r, l15, ks * 4 + kg);
                acc[r] = __builtin_amdgcn_mfma_f32_16x16x32_bf16(ah, bh, acc[r], 0, 0, 0);
                acc[r] = __builtin_amdgcn_mfma_f32_16x16x32_bf16(ah, bl, acc[r], 0, 0, 0);
                acc[r] = __builtin_amdgcn_mfma_f32_16x16x32_bf16(al, bh, acc[r], 0, 0, 0);
            }
        }
    }

#pragma unroll
    for (int r = 0; r < 16; ++r) {
#pragma unroll
        for (int q = 0; q < 4; ++q) {
            const int nl = nl0 + (lane >> 4) * 4 + q;
            const float val = acc[r][q];
            if (T == 0) {
                Pout[((size_t)nl * 16 + r) * KCH + j] = val;
            } else {
                const int n = base + nl;
                gout[(((size_t)PR_L[r] * NSAMP + n) * MDIM + PR_M[r]) * KCH + j] = val;
            }
        }
    }

    if (T == 1) {
        // zero-fill the 12 invalid (l,m) rows
        const int j2 = tid & 127;
        const int g  = tid >> 7;     // 0..3
#pragma unroll
        for (int z = 0; z < 12; ++z) {
#pragma unroll
            for (int i = 0; i < 4; ++i) {
                const int n = base + nl0 + g * 4 + i;
                gout[(((size_t)ZL[z] * NSAMP + n) * MDIM + ZM[z]) * KCH + j2] = 0.0f;
            }
        }
    }
}

extern "C" void kernel_launch(void* const* d_in, const int* in_sizes, int n_in,
                              void* d_out, int out_size, void* d_ws, size_t ws_size,
                              hipStream_t stream)
{
    const float* feats = (const float*)d_in[0];
    const float* U     = (const float*)d_in[1];
    const float* mW    = (const float*)d_in[2];
    const float* iW    = (const float*)d_in[3];
    float* out = (float*)d_out;

    // chunk size by workspace: per-sample = 3 * 16*128*4 B = 24576 B
    size_t avail = (ws_size > WP_BYTES) ? (ws_size - WP_BYTES) : 0;
    int NC = (int)(avail / 24576);
    NC = (NC / 16) * 16;
    if (NC > NSAMP) NC = NSAMP;
    if (NC < 16) return;   // workspace too small (not observed)

    char* wsb = (char*)d_ws;
    unsigned short* Wp = (unsigned short*)wsb;
    float* P0 = (float*)(wsb + WP_BYTES);
    float* P1 = P0 + (size_t)NC * 2048;
    float* P2 = P1 + (size_t)NC * 2048;

    hipFuncSetAttribute(reinterpret_cast<const void*>(cg_mix3),
                        hipFuncAttributeMaxDynamicSharedMemorySize, 131072);
    hipFuncSetAttribute(reinterpret_cast<const void*>(cg_fiter<0>),
                        hipFuncAttributeMaxDynamicSharedMemorySize, 131072);
    hipFuncSetAttribute(reinterpret_cast<const void*>(cg_fiter<1>),
                        hipFuncAttributeMaxDynamicSharedMemorySize, 131072);

    cg_prep<<<320, 256, 0, stream>>>(mW, iW, Wp);

    for (int base = 0; base < NSAMP; base += NC) {
        const int nc = (NSAMP - base < NC) ? (NSAMP - base) : NC;
        cg_mix3<<<nc / 16, 512, 131072, stream>>>(feats, (const bf16x8*)Wp, P0, P1, P2, base);
        // cur1 = P0 + mix(tp(P0,P1), iW0)  -> overwrite P1
        cg_fiter<0><<<nc / 16, 512, 131072, stream>>>(P0, P1, U, (const bf16x8*)Wp, P1, nullptr, base);
        // out  = P1 + mix(tp(P1,P2), iW1)
        cg_fiter<1><<<nc / 16, 512, 131072, stream>>>(P1, P2, U, (const bf16x8*)Wp, nullptr, out, base);
    }
}

// Round 7
// 561.766 us; speedup vs baseline: 1.4702x; 1.3135x over previous
//
#include <hip/hip_runtime.h>

#define NSAMP 4096
#define KCH   128
#define MDIM  7

typedef __attribute__((ext_vector_type(8))) short bf16x8;
typedef __attribute__((ext_vector_type(4))) float f32x4;

static constexpr int RB[4] = {0, 1, 4, 9};
static constexpr int RE[4] = {1, 4, 9, 16};
static constexpr int PR_L[16] = {0,1,1,1,2,2,2,2,2,3,3,3,3,3,3,3};
static constexpr int PR_M[16] = {0,0,1,2,0,1,2,3,4,0,1,2,3,4,5,6};

// CG paths in Python enumeration order
static constexpr int P_L1[34] = {0,1,2,3, 0,1,1,1,2,2,2,3,3, 0,1,1,1,2,2,2,2,3,3,3, 0,1,1,2,2,2,3,3,3,3};
static constexpr int P_L2[34] = {0,1,2,3, 1,0,1,2,1,2,3,2,3, 2,1,2,3,0,1,2,3,1,2,3, 3,2,3,1,2,3,0,1,2,3};
static constexpr int P_LO[34] = {0,0,0,0, 1,1,1,1,1,1,1,1,1, 2,2,2,2,2,2,2,2,2,2,2, 3,3,3,3,3,3,3,3,3,3};

// invalid (l,m) rows for zero-fill
static constexpr int ZL[12] = {0,0,0,0,0,0, 1,1,1,1, 2,2};
static constexpr int ZM[12] = {1,2,3,4,5,6, 3,4,5,6, 5,6};

#define WP_BYTES 1310720u   // 1280 sets * 512 shorts * 2B

static __device__ __forceinline__ unsigned short f2bf(float x) {
    unsigned u = __builtin_bit_cast(unsigned, x);
    u = u + 0x7FFFu + ((u >> 16) & 1u);
    return (unsigned short)(u >> 16);
}
static __device__ __forceinline__ float bf2f(unsigned short h) {
    unsigned u = ((unsigned)h) << 16;
    return __builtin_bit_cast(float, u);
}

// ---- TP path body, template-unrolled: ALL indices compile-time (rule #20 proof) ----
template<int P>
struct TPGen {
    static __device__ __forceinline__ void run(const float* __restrict__ Uc,
                                               const float (&cv)[16], const float (&mv)[16],
                                               float (&tv)[16]) {
        constexpr int l1 = P_L1[P], l2 = P_L2[P], Lo = P_LO[P];
        const float* __restrict__ Up = Uc + P * 343;
#pragma unroll
        for (int a = 0; a < 2 * l1 + 1; ++a) {
#pragma unroll
            for (int b = 0; b < 2 * l2 + 1; ++b) {
                const float prod = cv[RB[l1] + a] * mv[RB[l2] + b];
#pragma unroll
                for (int c = 0; c < 2 * Lo + 1; ++c) {
                    tv[RB[Lo] + c] += prod * Up[(a * 7 + b) * 7 + c];
                }
            }
        }
        TPGen<P + 1>::run(Uc, cv, mv, tv);
    }
};
template<>
struct TPGen<34> {
    static __device__ __forceinline__ void run(const float*, const float (&)[16],
                                               const float (&)[16], float (&)[16]) {}
};

// ---------------- K0: W -> bf16 hi/lo in B-fragment order ----------------
__global__ __launch_bounds__(256) void cg_prep(const float* __restrict__ mW,
                                               const float* __restrict__ iW,
                                               unsigned short* __restrict__ Wp)
{
    int gid = blockIdx.x * 256 + threadIdx.x;
    int lane = gid & 63;
    int set  = gid >> 6;                            // 1280 sets
    int spl = set & 1;
    int ks  = (set >> 1) & 3;
    int ct  = (set >> 3) & 7;
    int l   = (set >> 6) & 3;
    int mi  = set >> 8;                             // 0..4
    const float* src = (mi < 3) ? (mW + ((size_t)mi * 4 + l) * (KCH * KCH))
                                : (iW + ((size_t)(mi - 3) * 4 + l) * (KCH * KCH));
    int j  = ct * 16 + (lane & 15);
    int kb = ks * 32 + (lane >> 4) * 8;
    unsigned short o[8];
#pragma unroll
    for (int e = 0; e < 8; ++e) {
        float w = src[(size_t)(kb + e) * KCH + j];
        unsigned short h = f2bf(w);
        o[e] = spl ? f2bf(w - bf2f(h)) : h;
    }
    uint4 pk;
    unsigned* pw = (unsigned*)&pk;
#pragma unroll
    for (int q = 0; q < 4; ++q) pw[q] = (unsigned)o[2*q] | ((unsigned)o[2*q+1] << 16);
    *(uint4*)(Wp + (size_t)set * 512 + lane * 8) = pk;
}

// A-fragment read from bf16 plane [256 rows][128], chunk-XOR swizzled by (key&7)
static __device__ __forceinline__ bf16x8 ldF(const unsigned short* P, int row16, int key, int c) {
    int cs = c ^ (key & 7);
    return *(const bf16x8*)(P + row16 * 128 + cs * 8);
}

// ---------------- K2: three mixer GEMMs, rows = samples (3 sequential sweeps) ----------------
__global__ __launch_bounds__(512, 2) void cg_mix3(const float* __restrict__ feats,
                                                  const bf16x8* __restrict__ Wp,
                                                  float* __restrict__ P0,
                                                  float* __restrict__ P1,
                                                  float* __restrict__ P2,
                                                  int base)
{
    extern __shared__ char smem[];
    unsigned short* Fh = (unsigned short*)smem;            // 64 KB: [256 rows][128]
    unsigned short* Fl = Fh + 32768;                       // 64 KB

    const int tid  = threadIdx.x;
    const int lane = tid & 63;
    const int ct   = tid >> 6;              // wave id = j col-tile
    const int nl0  = blockIdx.x * 16;       // chunk-local sample base

    // ---- stage feats -> hi/lo bf16 LDS, rows (r,n), XOR-swizzled chunks ----
    {
        const int row = tid >> 1;           // 0..255 = r*16 + nlr
        const int r   = row >> 4;
        const int nlr = row & 15;
        const int kh  = tid & 1;
        const int l = PR_L[r], m = PR_M[r];
        const float* g = feats + (((size_t)l * NSAMP + (base + nl0 + nlr)) * MDIM + m) * KCH + kh * 64;
        unsigned short* fh = Fh + row * 128;
        unsigned short* fl = Fl + row * 128;
#pragma unroll
        for (int c8 = 0; c8 < 8; ++c8) {
            f32x4 a = *(const f32x4*)(g + c8 * 8);
            f32x4 b = *(const f32x4*)(g + c8 * 8 + 4);
            float v[8] = {a[0], a[1], a[2], a[3], b[0], b[1], b[2], b[3]};
            unsigned short hi[8], lo[8];
#pragma unroll
            for (int i = 0; i < 8; ++i) {
                hi[i] = f2bf(v[i]);
                lo[i] = f2bf(v[i] - bf2f(hi[i]));
            }
            uint4 ph, pl;
            unsigned* pwh = (unsigned*)&ph;
            unsigned* pwl = (unsigned*)&pl;
#pragma unroll
            for (int q = 0; q < 4; ++q) {
                pwh[q] = (unsigned)hi[2*q] | ((unsigned)hi[2*q+1] << 16);
                pwl[q] = (unsigned)lo[2*q] | ((unsigned)lo[2*q+1] << 16);
            }
            const int cs = (kh * 8 + c8) ^ (nlr & 7);
            *(uint4*)(fh + cs * 8) = ph;
            *(uint4*)(fl + cs * 8) = pl;
        }
    }
    __syncthreads();

    const int kg = lane >> 4;
    const int l15 = lane & 15;
    const int j = ct * 16 + l15;

#pragma unroll 1
    for (int mi = 0; mi < 3; ++mi) {
        f32x4 acc[16];
#pragma unroll
        for (int r = 0; r < 16; ++r) { acc[r][0]=acc[r][1]=acc[r][2]=acc[r][3]=0.0f; }
#pragma unroll
        for (int ks = 0; ks < 4; ++ks) {
#pragma unroll
            for (int l = 0; l < 4; ++l) {
                const int s0 = (((mi * 4 + l) * 8 + ct) * 4 + ks) * 2;
                bf16x8 bh = Wp[(size_t)s0 * 64 + lane];
                bf16x8 bl = Wp[(size_t)(s0 + 1) * 64 + lane];
#pragma unroll
                for (int r = RB[l]; r < RE[l]; ++r) {
                    bf16x8 ah = ldF(Fh, r * 16 + l15, l15, ks * 4 + kg);
                    bf16x8 al = ldF(Fl, r * 16 + l15, l15, ks * 4 + kg);
                    acc[r] = __builtin_amdgcn_mfma_f32_16x16x32_bf16(ah, bh, acc[r], 0, 0, 0);
                    acc[r] = __builtin_amdgcn_mfma_f32_16x16x32_bf16(ah, bl, acc[r], 0, 0, 0);
                    acc[r] = __builtin_amdgcn_mfma_f32_16x16x32_bf16(al, bh, acc[r], 0, 0, 0);
                }
            }
        }
        float* Pd = (mi == 0) ? P0 : (mi == 1) ? P1 : P2;
#pragma unroll
        for (int r = 0; r < 16; ++r) {
#pragma unroll
            for (int q = 0; q < 4; ++q) {
                const int nl = nl0 + (lane >> 4) * 4 + q;
                Pd[((size_t)nl * 16 + r) * KCH + j] = acc[r][q];
            }
        }
    }
}

// ---------------- K3: tensor product, per-thread (n,k), f32 linear output ----------------
__global__ __launch_bounds__(256, 4) void cg_tp(const float* __restrict__ Pc,
                                                const float* __restrict__ Pm,
                                                float* __restrict__ Pt,
                                                const float* __restrict__ Uc)
{
    const int tid = threadIdx.x;
    const int nl = blockIdx.x * 2 + (tid >> 7);
    const int tj = tid & 127;

    float cv[16], mv[16], tv[16];
#pragma unroll
    for (int r = 0; r < 16; ++r) {
        cv[r] = Pc[((size_t)nl * 16 + r) * KCH + tj];
        mv[r] = Pm[((size_t)nl * 16 + r) * KCH + tj];
        tv[r] = 0.0f;
    }
    TPGen<0>::run(Uc, cv, mv, tv);
#pragma unroll
    for (int r = 0; r < 16; ++r) {
        Pt[((size_t)nl * 16 + r) * KCH + tj] = tv[r];
    }
}

// ---------------- K4: iter mix + residual (T=0 -> Pout, T=1 -> final out) ----------------
template<int T>
__global__ __launch_bounds__(512, 2) void cg_iter(const float* __restrict__ Pt,
                                                  const bf16x8* __restrict__ Wp,
                                                  const float* __restrict__ Pres,
                                                  float* __restrict__ Pout,
                                                  float* __restrict__ gout,
                                                  int base)
{
    extern __shared__ char smem[];
    unsigned short* Th = (unsigned short*)smem;   // 64 KB: [256 rows][128]
    unsigned short* Tl = Th + 32768;              // 64 KB

    const int tid  = threadIdx.x;
    const int lane = tid & 63;
    const int ct   = tid >> 6;
    const int nl0  = blockIdx.x * 16;

    // ---- stage tp (f32, linear) -> hi/lo bf16 LDS, XOR-swizzled (mix3-proven pattern) ----
    {
        const int row = tid >> 1;           // 0..255 = nl*16 + r
        const int kh  = tid & 1;
        const float* g = Pt + ((size_t)(nl0 * 16) + row) * KCH + kh * 64;
        unsigned short* fh = Th + row * 128;
        unsigned short* fl = Tl + row * 128;
        const int key = (row >> 4) & 7;     // sample index within tile
#pragma unroll
        for (int c8 = 0; c8 < 8; ++c8) {
            f32x4 a = *(const f32x4*)(g + c8 * 8);
            f32x4 b = *(const f32x4*)(g + c8 * 8 + 4);
            float v[8] = {a[0], a[1], a[2], a[3], b[0], b[1], b[2], b[3]};
            unsigned short hi[8], lo[8];
#pragma unroll
            for (int i = 0; i < 8; ++i) {
                hi[i] = f2bf(v[i]);
                lo[i] = f2bf(v[i] - bf2f(hi[i]));
            }
            uint4 ph, pl;
            unsigned* pwh = (unsigned*)&ph;
            unsigned* pwl = (unsigned*)&pl;
#pragma unroll
            for (int q = 0; q < 4; ++q) {
                pwh[q] = (unsigned)hi[2*q] | ((unsigned)hi[2*q+1] << 16);
                pwl[q] = (unsigned)lo[2*q] | ((unsigned)lo[2*q+1] << 16);
            }
            const int cs = (kh * 8 + c8) ^ key;
            *(uint4*)(fh + cs * 8) = ph;
            *(uint4*)(fl + cs * 8) = pl;
        }
    }
    __syncthreads();

    const int kg = lane >> 4;
    const int l15 = lane & 15;
    const int j = ct * 16 + l15;

    f32x4 acc[16];
#pragma unroll
    for (int r = 0; r < 16; ++r) { acc[r][0]=acc[r][1]=acc[r][2]=acc[r][3]=0.0f; }

#pragma unroll
    for (int ks = 0; ks < 4; ++ks) {
#pragma unroll
        for (int l = 0; l < 4; ++l) {
            const int s0 = ((((3 + T) * 4 + l) * 8 + ct) * 4 + ks) * 2;
            bf16x8 bh = Wp[(size_t)s0 * 64 + lane];
            bf16x8 bl = Wp[(size_t)(s0 + 1) * 64 + lane];
#pragma unroll
            for (int r = RB[l]; r < RE[l]; ++r) {
                // rows of tp plane are nl*16 + r, swizzle key = nl&7
                bf16x8 ah = ldF(Th, l15 * 16 + r, l15, ks * 4 + kg);
                bf16x8 al = ldF(Tl, l15 * 16 + r, l15, ks * 4 + kg);
                acc[r] = __builtin_amdgcn_mfma_f32_16x16x32_bf16(ah, bh, acc[r], 0, 0, 0);
                acc[r] = __builtin_amdgcn_mfma_f32_16x16x32_bf16(ah, bl, acc[r], 0, 0, 0);
                acc[r] = __builtin_amdgcn_mfma_f32_16x16x32_bf16(al, bh, acc[r], 0, 0, 0);
            }
        }
    }

#pragma unroll
    for (int r = 0; r < 16; ++r) {
#pragma unroll
        for (int q = 0; q < 4; ++q) {
            const int nl = nl0 + (lane >> 4) * 4 + q;
            const float val = acc[r][q] + Pres[((size_t)nl * 16 + r) * KCH + j];
            if (T == 0) {
                Pout[((size_t)nl * 16 + r) * KCH + j] = val;
            } else {
                const int n = base + nl;
                gout[(((size_t)PR_L[r] * NSAMP + n) * MDIM + PR_M[r]) * KCH + j] = val;
            }
        }
    }

    if (T == 1) {
        // zero-fill the 12 invalid (l,m) rows
        const int j2 = tid & 127;
        const int g  = tid >> 7;     // 0..3
#pragma unroll
        for (int z = 0; z < 12; ++z) {
#pragma unroll
            for (int i = 0; i < 4; ++i) {
                const int n = base + nl0 + g * 4 + i;
                gout[(((size_t)ZL[z] * NSAMP + n) * MDIM + ZM[z]) * KCH + j2] = 0.0f;
            }
        }
    }
}

extern "C" void kernel_launch(void* const* d_in, const int* in_sizes, int n_in,
                              void* d_out, int out_size, void* d_ws, size_t ws_size,
                              hipStream_t stream)
{
    const float* feats = (const float*)d_in[0];
    const float* U     = (const float*)d_in[1];
    const float* mW    = (const float*)d_in[2];
    const float* iW    = (const float*)d_in[3];
    float* out = (float*)d_out;

    // chunk size by workspace: per-sample = 4 * 16*128*4 B = 32768 B (P0,P1,P2,Pt)
    size_t avail = (ws_size > WP_BYTES) ? (ws_size - WP_BYTES) : 0;
    int NC = (int)(avail / 32768);
    NC = (NC / 16) * 16;
    if (NC > NSAMP) NC = NSAMP;
    if (NC < 16) return;   // workspace too small (not observed)

    char* wsb = (char*)d_ws;
    unsigned short* Wp = (unsigned short*)wsb;
    float* P0 = (float*)(wsb + WP_BYTES);
    float* P1 = P0 + (size_t)NC * 2048;
    float* P2 = P1 + (size_t)NC * 2048;
    float* Pt = P2 + (size_t)NC * 2048;

    hipFuncSetAttribute(reinterpret_cast<const void*>(cg_mix3),
                        hipFuncAttributeMaxDynamicSharedMemorySize, 131072);
    hipFuncSetAttribute(reinterpret_cast<const void*>(cg_iter<0>),
                        hipFuncAttributeMaxDynamicSharedMemorySize, 131072);
    hipFuncSetAttribute(reinterpret_cast<const void*>(cg_iter<1>),
                        hipFuncAttributeMaxDynamicSharedMemorySize, 131072);

    cg_prep<<<320, 256, 0, stream>>>(mW, iW, Wp);

    for (int base = 0; base < NSAMP; base += NC) {
        const int nc = (NSAMP - base < NC) ? (NSAMP - base) : NC;
        cg_mix3<<<nc / 16, 512, 131072, stream>>>(feats, (const bf16x8*)Wp, P0, P1, P2, base);
        // tp = TP(P0, P1); cur1 = P0 + mix(tp, iW0) -> overwrite P1
        cg_tp<<<nc / 2, 256, 0, stream>>>(P0, P1, Pt, U);
        cg_iter<0><<<nc / 16, 512, 131072, stream>>>(Pt, (const bf16x8*)Wp, P0, P1, nullptr, base);
        // tp = TP(P1, P2); out = P1 + mix(tp, iW1)
        cg_tp<<<nc / 2, 256, 0, stream>>>(P1, P2, Pt, U);
        cg_iter<1><<<nc / 16, 512, 131072, stream>>>(Pt, (const bf16x8*)Wp, P1, nullptr, out, base);
    }
}

// Round 8
// 314.257 us; speedup vs baseline: 2.6281x; 1.7876x over previous
//
#include <hip/hip_runtime.h>

#define NSAMP 4096
#define KCH   128
#define MDIM  7

typedef __attribute__((ext_vector_type(8))) short bf16x8;
typedef __attribute__((ext_vector_type(4))) float f32x4;

static constexpr int RB[4] = {0, 1, 4, 9};
static constexpr int RE[4] = {1, 4, 9, 16};
static constexpr int PR_L[16] = {0,1,1,1,2,2,2,2,2,3,3,3,3,3,3,3};
static constexpr int PR_M[16] = {0,0,1,2,0,1,2,3,4,0,1,2,3,4,5,6};

// CG paths in Python enumeration order
static constexpr int P_L1[34] = {0,1,2,3, 0,1,1,1,2,2,2,3,3, 0,1,1,1,2,2,2,2,3,3,3, 0,1,1,2,2,2,3,3,3,3};
static constexpr int P_L2[34] = {0,1,2,3, 1,0,1,2,1,2,3,2,3, 2,1,2,3,0,1,2,3,1,2,3, 3,2,3,1,2,3,0,1,2,3};
static constexpr int P_LO[34] = {0,0,0,0, 1,1,1,1,1,1,1,1,1, 2,2,2,2,2,2,2,2,2,2,2, 3,3,3,3,3,3,3,3,3,3};

// invalid (l,m) rows for zero-fill
static constexpr int ZL[12] = {0,0,0,0,0,0, 1,1,1,1, 2,2};
static constexpr int ZM[12] = {1,2,3,4,5,6, 3,4,5,6, 5,6};

#define WP_BYTES 1310720u   // 1280 sets * 512 shorts * 2B

static __device__ __forceinline__ unsigned short f2bf(float x) {
    unsigned u = __builtin_bit_cast(unsigned, x);
    u = u + 0x7FFFu + ((u >> 16) & 1u);
    return (unsigned short)(u >> 16);
}
static __device__ __forceinline__ float bf2f(unsigned short h) {
    unsigned u = ((unsigned)h) << 16;
    return __builtin_bit_cast(float, u);
}

// ---- TP path body, template-unrolled: ALL indices compile-time ----
template<int P>
struct TPGen {
    static __device__ __forceinline__ void run(const float* __restrict__ Uc,
                                               const float (&cv)[16], const float (&mv)[16],
                                               float (&tv)[16]) {
        constexpr int l1 = P_L1[P], l2 = P_L2[P], Lo = P_LO[P];
        const float* __restrict__ Up = Uc + P * 343;
#pragma unroll
        for (int a = 0; a < 2 * l1 + 1; ++a) {
#pragma unroll
            for (int b = 0; b < 2 * l2 + 1; ++b) {
                const float prod = cv[RB[l1] + a] * mv[RB[l2] + b];
#pragma unroll
                for (int c = 0; c < 2 * Lo + 1; ++c) {
                    tv[RB[Lo] + c] += prod * Up[(a * 7 + b) * 7 + c];
                }
            }
        }
        TPGen<P + 1>::run(Uc, cv, mv, tv);
    }
};
template<>
struct TPGen<34> {
    static __device__ __forceinline__ void run(const float*, const float (&)[16],
                                               const float (&)[16], float (&)[16]) {}
};

// ---------------- K0: W -> bf16 hi/lo in B-fragment order ----------------
__global__ __launch_bounds__(256) void cg_prep(const float* __restrict__ mW,
                                               const float* __restrict__ iW,
                                               unsigned short* __restrict__ Wp)
{
    int gid = blockIdx.x * 256 + threadIdx.x;
    int lane = gid & 63;
    int set  = gid >> 6;                            // 1280 sets
    int spl = set & 1;
    int ks  = (set >> 1) & 3;
    int ct  = (set >> 3) & 7;
    int l   = (set >> 6) & 3;
    int mi  = set >> 8;                             // 0..4
    const float* src = (mi < 3) ? (mW + ((size_t)mi * 4 + l) * (KCH * KCH))
                                : (iW + ((size_t)(mi - 3) * 4 + l) * (KCH * KCH));
    int j  = ct * 16 + (lane & 15);
    int kb = ks * 32 + (lane >> 4) * 8;
    unsigned short o[8];
#pragma unroll
    for (int e = 0; e < 8; ++e) {
        float w = src[(size_t)(kb + e) * KCH + j];
        unsigned short h = f2bf(w);
        o[e] = spl ? f2bf(w - bf2f(h)) : h;
    }
    uint4 pk;
    unsigned* pw = (unsigned*)&pk;
#pragma unroll
    for (int q = 0; q < 4; ++q) pw[q] = (unsigned)o[2*q] | ((unsigned)o[2*q+1] << 16);
    *(uint4*)(Wp + (size_t)set * 512 + lane * 8) = pk;
}

// A-fragment read from bf16 plane [256 rows][128], chunk-XOR swizzled by (key&7)
static __device__ __forceinline__ bf16x8 ldF(const unsigned short* P, int row16, int key, int c) {
    int cs = c ^ (key & 7);
    return *(const bf16x8*)(P + row16 * 128 + cs * 8);
}

// ---------------- K2: three mixer GEMMs, rows = samples (R4-proven straight-line) ----------------
__global__ __launch_bounds__(512, 2) void cg_mix3(const float* __restrict__ feats,
                                                  const bf16x8* __restrict__ Wp,
                                                  float* __restrict__ P0,
                                                  float* __restrict__ P1,
                                                  float* __restrict__ P2,
                                                  int base)
{
    extern __shared__ char smem[];
    unsigned short* Fh = (unsigned short*)smem;            // 64 KB: [256 rows][128]
    unsigned short* Fl = Fh + 32768;                       // 64 KB

    const int tid  = threadIdx.x;
    const int lane = tid & 63;
    const int ct   = tid >> 6;              // wave id = j col-tile
    const int nl0  = blockIdx.x * 16;       // chunk-local sample base

    // ---- stage feats -> hi/lo bf16 LDS, rows (r,n), XOR-swizzled chunks ----
    {
        const int row = tid >> 1;           // 0..255 = r*16 + nlr
        const int r   = row >> 4;
        const int nlr = row & 15;
        const int kh  = tid & 1;
        const int l = PR_L[r], m = PR_M[r];
        const float* g = feats + (((size_t)l * NSAMP + (base + nl0 + nlr)) * MDIM + m) * KCH + kh * 64;
        unsigned short* fh = Fh + row * 128;
        unsigned short* fl = Fl + row * 128;
#pragma unroll
        for (int c8 = 0; c8 < 8; ++c8) {
            f32x4 a = *(const f32x4*)(g + c8 * 8);
            f32x4 b = *(const f32x4*)(g + c8 * 8 + 4);
            float v[8] = {a[0], a[1], a[2], a[3], b[0], b[1], b[2], b[3]};
            unsigned short hi[8], lo[8];
#pragma unroll
            for (int i = 0; i < 8; ++i) {
                hi[i] = f2bf(v[i]);
                lo[i] = f2bf(v[i] - bf2f(hi[i]));
            }
            uint4 ph, pl;
            unsigned* pwh = (unsigned*)&ph;
            unsigned* pwl = (unsigned*)&pl;
#pragma unroll
            for (int q = 0; q < 4; ++q) {
                pwh[q] = (unsigned)hi[2*q] | ((unsigned)hi[2*q+1] << 16);
                pwl[q] = (unsigned)lo[2*q] | ((unsigned)lo[2*q+1] << 16);
            }
            const int cs = (kh * 8 + c8) ^ (nlr & 7);
            *(uint4*)(fh + cs * 8) = ph;
            *(uint4*)(fl + cs * 8) = pl;
        }
    }
    __syncthreads();

    const int kg = lane >> 4;
    const int l15 = lane & 15;
    const int j = ct * 16 + l15;

    // ---- dual sweep: mi = 0 and 1 (shares A-fragment loads) ----
    f32x4 acc0[16], acc1[16];
#pragma unroll
    for (int r = 0; r < 16; ++r) {
        acc0[r][0]=acc0[r][1]=acc0[r][2]=acc0[r][3]=0.0f;
        acc1[r][0]=acc1[r][1]=acc1[r][2]=acc1[r][3]=0.0f;
    }
#pragma unroll
    for (int ks = 0; ks < 4; ++ks) {
#pragma unroll
        for (int l = 0; l < 4; ++l) {
            const int s0 = (((0 * 4 + l) * 8 + ct) * 4 + ks) * 2;
            const int s1 = (((1 * 4 + l) * 8 + ct) * 4 + ks) * 2;
            bf16x8 b0h = Wp[(size_t)s0 * 64 + lane];
            bf16x8 b0l = Wp[(size_t)(s0 + 1) * 64 + lane];
            bf16x8 b1h = Wp[(size_t)s1 * 64 + lane];
            bf16x8 b1l = Wp[(size_t)(s1 + 1) * 64 + lane];
#pragma unroll
            for (int r = RB[l]; r < RE[l]; ++r) {
                bf16x8 ah = ldF(Fh, r * 16 + l15, l15, ks * 4 + kg);
                bf16x8 al = ldF(Fl, r * 16 + l15, l15, ks * 4 + kg);
                acc0[r] = __builtin_amdgcn_mfma_f32_16x16x32_bf16(ah, b0h, acc0[r], 0, 0, 0);
                acc0[r] = __builtin_amdgcn_mfma_f32_16x16x32_bf16(ah, b0l, acc0[r], 0, 0, 0);
                acc0[r] = __builtin_amdgcn_mfma_f32_16x16x32_bf16(al, b0h, acc0[r], 0, 0, 0);
                acc1[r] = __builtin_amdgcn_mfma_f32_16x16x32_bf16(ah, b1h, acc1[r], 0, 0, 0);
                acc1[r] = __builtin_amdgcn_mfma_f32_16x16x32_bf16(ah, b1l, acc1[r], 0, 0, 0);
                acc1[r] = __builtin_amdgcn_mfma_f32_16x16x32_bf16(al, b1h, acc1[r], 0, 0, 0);
            }
        }
    }
#pragma unroll
    for (int r = 0; r < 16; ++r) {
#pragma unroll
        for (int q = 0; q < 4; ++q) {
            const int nl = nl0 + (lane >> 4) * 4 + q;
            P0[((size_t)nl * 16 + r) * KCH + j] = acc0[r][q];
            P1[((size_t)nl * 16 + r) * KCH + j] = acc1[r][q];
        }
    }

    // ---- single sweep: mi = 2 ----
#pragma unroll
    for (int r = 0; r < 16; ++r) { acc0[r][0]=acc0[r][1]=acc0[r][2]=acc0[r][3]=0.0f; }
#pragma unroll
    for (int ks = 0; ks < 4; ++ks) {
#pragma unroll
        for (int l = 0; l < 4; ++l) {
            const int s0 = (((2 * 4 + l) * 8 + ct) * 4 + ks) * 2;
            bf16x8 bh = Wp[(size_t)s0 * 64 + lane];
            bf16x8 bl = Wp[(size_t)(s0 + 1) * 64 + lane];
#pragma unroll
            for (int r = RB[l]; r < RE[l]; ++r) {
                bf16x8 ah = ldF(Fh, r * 16 + l15, l15, ks * 4 + kg);
                bf16x8 al = ldF(Fl, r * 16 + l15, l15, ks * 4 + kg);
                acc0[r] = __builtin_amdgcn_mfma_f32_16x16x32_bf16(ah, bh, acc0[r], 0, 0, 0);
                acc0[r] = __builtin_amdgcn_mfma_f32_16x16x32_bf16(ah, bl, acc0[r], 0, 0, 0);
                acc0[r] = __builtin_amdgcn_mfma_f32_16x16x32_bf16(al, bh, acc0[r], 0, 0, 0);
            }
        }
    }
#pragma unroll
    for (int r = 0; r < 16; ++r) {
#pragma unroll
        for (int q = 0; q < 4; ++q) {
            const int nl = nl0 + (lane >> 4) * 4 + q;
            P2[((size_t)nl * 16 + r) * KCH + j] = acc0[r][q];
        }
    }
}

// ---------------- K3: tensor product, per-thread (n,k), f32 linear output ----------------
__global__ __launch_bounds__(256, 4) void cg_tp(const float* __restrict__ Pc,
                                                const float* __restrict__ Pm,
                                                float* __restrict__ Pt,
                                                const float* __restrict__ Uc)
{
    const int tid = threadIdx.x;
    const int nl = blockIdx.x * 2 + (tid >> 7);
    const int tj = tid & 127;

    float cv[16], mv[16], tv[16];
#pragma unroll
    for (int r = 0; r < 16; ++r) {
        cv[r] = Pc[((size_t)nl * 16 + r) * KCH + tj];
        mv[r] = Pm[((size_t)nl * 16 + r) * KCH + tj];
        tv[r] = 0.0f;
    }
    TPGen<0>::run(Uc, cv, mv, tv);
#pragma unroll
    for (int r = 0; r < 16; ++r) {
        Pt[((size_t)nl * 16 + r) * KCH + tj] = tv[r];
    }
}

// ---------------- K4: iter mix + residual (T=0 -> Pout, T=1 -> final out) ----------------
template<int T>
__global__ __launch_bounds__(512, 2) void cg_iter(const float* __restrict__ Pt,
                                                  const bf16x8* __restrict__ Wp,
                                                  const float* __restrict__ Pres,
                                                  float* __restrict__ Pout,
                                                  float* __restrict__ gout,
                                                  int base)
{
    extern __shared__ char smem[];
    unsigned short* Th = (unsigned short*)smem;   // 64 KB: [256 rows][128]
    unsigned short* Tl = Th + 32768;              // 64 KB

    const int tid  = threadIdx.x;
    const int lane = tid & 63;
    const int ct   = tid >> 6;
    const int nl0  = blockIdx.x * 16;

    // ---- stage tp (f32, linear) -> hi/lo bf16 LDS, XOR-swizzled ----
    {
        const int row = tid >> 1;           // 0..255 = nl*16 + r
        const int kh  = tid & 1;
        const float* g = Pt + ((size_t)(nl0 * 16) + row) * KCH + kh * 64;
        unsigned short* fh = Th + row * 128;
        unsigned short* fl = Tl + row * 128;
        const int key = (row >> 4) & 7;     // sample index within tile
#pragma unroll
        for (int c8 = 0; c8 < 8; ++c8) {
            f32x4 a = *(const f32x4*)(g + c8 * 8);
            f32x4 b = *(const f32x4*)(g + c8 * 8 + 4);
            float v[8] = {a[0], a[1], a[2], a[3], b[0], b[1], b[2], b[3]};
            unsigned short hi[8], lo[8];
#pragma unroll
            for (int i = 0; i < 8; ++i) {
                hi[i] = f2bf(v[i]);
                lo[i] = f2bf(v[i] - bf2f(hi[i]));
            }
            uint4 ph, pl;
            unsigned* pwh = (unsigned*)&ph;
            unsigned* pwl = (unsigned*)&pl;
#pragma unroll
            for (int q = 0; q < 4; ++q) {
                pwh[q] = (unsigned)hi[2*q] | ((unsigned)hi[2*q+1] << 16);
                pwl[q] = (unsigned)lo[2*q] | ((unsigned)lo[2*q+1] << 16);
            }
            const int cs = (kh * 8 + c8) ^ key;
            *(uint4*)(fh + cs * 8) = ph;
            *(uint4*)(fl + cs * 8) = pl;
        }
    }
    __syncthreads();

    const int kg = lane >> 4;
    const int l15 = lane & 15;
    const int j = ct * 16 + l15;

    f32x4 acc[16];
#pragma unroll
    for (int r = 0; r < 16; ++r) { acc[r][0]=acc[r][1]=acc[r][2]=acc[r][3]=0.0f; }

#pragma unroll
    for (int ks = 0; ks < 4; ++ks) {
#pragma unroll
        for (int l = 0; l < 4; ++l) {
            const int s0 = ((((3 + T) * 4 + l) * 8 + ct) * 4 + ks) * 2;
            bf16x8 bh = Wp[(size_t)s0 * 64 + lane];
            bf16x8 bl = Wp[(size_t)(s0 + 1) * 64 + lane];
#pragma unroll
            for (int r = RB[l]; r < RE[l]; ++r) {
                bf16x8 ah = ldF(Th, l15 * 16 + r, l15, ks * 4 + kg);
                bf16x8 al = ldF(Tl, l15 * 16 + r, l15, ks * 4 + kg);
                acc[r] = __builtin_amdgcn_mfma_f32_16x16x32_bf16(ah, bh, acc[r], 0, 0, 0);
                acc[r] = __builtin_amdgcn_mfma_f32_16x16x32_bf16(ah, bl, acc[r], 0, 0, 0);
                acc[r] = __builtin_amdgcn_mfma_f32_16x16x32_bf16(al, bh, acc[r], 0, 0, 0);
            }
        }
    }

#pragma unroll
    for (int r = 0; r < 16; ++r) {
#pragma unroll
        for (int q = 0; q < 4; ++q) {
            const int nl = nl0 + (lane >> 4) * 4 + q;
            const float val = acc[r][q] + Pres[((size_t)nl * 16 + r) * KCH + j];
            if (T == 0) {
                Pout[((size_t)nl * 16 + r) * KCH + j] = val;
            } else {
                const int n = base + nl;
                gout[(((size_t)PR_L[r] * NSAMP + n) * MDIM + PR_M[r]) * KCH + j] = val;
            }
        }
    }

    if (T == 1) {
        // zero-fill the 12 invalid (l,m) rows
        const int j2 = tid & 127;
        const int g  = tid >> 7;     // 0..3
#pragma unroll
        for (int z = 0; z < 12; ++z) {
#pragma unroll
            for (int i = 0; i < 4; ++i) {
                const int n = base + nl0 + g * 4 + i;
                gout[(((size_t)ZL[z] * NSAMP + n) * MDIM + ZM[z]) * KCH + j2] = 0.0f;
            }
        }
    }
}

extern "C" void kernel_launch(void* const* d_in, const int* in_sizes, int n_in,
                              void* d_out, int out_size, void* d_ws, size_t ws_size,
                              hipStream_t stream)
{
    const float* feats = (const float*)d_in[0];
    const float* U     = (const float*)d_in[1];
    const float* mW    = (const float*)d_in[2];
    const float* iW    = (const float*)d_in[3];
    float* out = (float*)d_out;

    // chunk size by workspace: per-sample = 4 * 16*128*4 B = 32768 B (P0,P1,P2,Pt)
    size_t avail = (ws_size > WP_BYTES) ? (ws_size - WP_BYTES) : 0;
    int NC = (int)(avail / 32768);
    NC = (NC / 16) * 16;
    if (NC > NSAMP) NC = NSAMP;
    if (NC < 16) return;   // workspace too small (not observed)

    char* wsb = (char*)d_ws;
    unsigned short* Wp = (unsigned short*)wsb;
    float* P0 = (float*)(wsb + WP_BYTES);
    float* P1 = P0 + (size_t)NC * 2048;
    float* P2 = P1 + (size_t)NC * 2048;
    float* Pt = P2 + (size_t)NC * 2048;

    hipFuncSetAttribute(reinterpret_cast<const void*>(cg_mix3),
                        hipFuncAttributeMaxDynamicSharedMemorySize, 131072);
    hipFuncSetAttribute(reinterpret_cast<const void*>(cg_iter<0>),
                        hipFuncAttributeMaxDynamicSharedMemorySize, 131072);
    hipFuncSetAttribute(reinterpret_cast<const void*>(cg_iter<1>),
                        hipFuncAttributeMaxDynamicSharedMemorySize, 131072);

    cg_prep<<<320, 256, 0, stream>>>(mW, iW, Wp);

    for (int base = 0; base < NSAMP; base += NC) {
        const int nc = (NSAMP - base < NC) ? (NSAMP - base) : NC;
        cg_mix3<<<nc / 16, 512, 131072, stream>>>(feats, (const bf16x8*)Wp, P0, P1, P2, base);
        // tp = TP(P0, P1); cur1 = P0 + mix(tp, iW0) -> overwrite P1
        cg_tp<<<nc / 2, 256, 0, stream>>>(P0, P1, Pt, U);
        cg_iter<0><<<nc / 16, 512, 131072, stream>>>(Pt, (const bf16x8*)Wp, P0, P1, nullptr, base);
        // tp = TP(P1, P2); out = P1 + mix(tp, iW1)
        cg_tp<<<nc / 2, 256, 0, stream>>>(P1, P2, Pt, U);
        cg_iter<1><<<nc / 16, 512, 131072, stream>>>(Pt, (const bf16x8*)Wp, P1, nullptr, out, base);
    }
}

// Round 9
// 154.223 us; speedup vs baseline: 5.3552x; 2.0377x over previous
//
#include <hip/hip_runtime.h>

#define NSAMP 4096
#define KCH   128
#define MDIM  7

typedef __attribute__((ext_vector_type(8))) short bf16x8;
typedef __attribute__((ext_vector_type(4))) float f32x4;
typedef __attribute__((ext_vector_type(4))) unsigned u32x4;

static constexpr int RB[4] = {0, 1, 4, 9};
static constexpr int RE[4] = {1, 4, 9, 16};
static constexpr int PR_L[16] = {0,1,1,1,2,2,2,2,2,3,3,3,3,3,3,3};
static constexpr int PR_M[16] = {0,0,1,2,0,1,2,3,4,0,1,2,3,4,5,6};

// path index by (L, l1, l2); -1 = no path  (Python enumeration order)
static constexpr int PIDX[4][4][4] = {
  { { 0,-1,-1,-1},{-1, 1,-1,-1},{-1,-1, 2,-1},{-1,-1,-1, 3} },
  { {-1, 4,-1,-1},{ 5, 6, 7,-1},{-1, 8, 9,10},{-1,-1,11,12} },
  { {-1,-1,13,-1},{-1,14,15,16},{17,18,19,20},{-1,21,22,23} },
  { {-1,-1,-1,24},{-1,-1,25,26},{-1,27,28,29},{30,31,32,33} }
};

// invalid (l,m) rows for zero-fill
static constexpr int ZL[12] = {0,0,0,0,0,0, 1,1,1,1, 2,2};
static constexpr int ZM[12] = {1,2,3,4,5,6, 3,4,5,6, 5,6};

#define WP_BYTES 1310720u   // 1280 sets * 512 shorts * 2B
#define BG_BYTES 16384u     // G matrix: 8 steps * 2(hi/lo) * 64 lanes * 8 bf16

static __device__ __forceinline__ unsigned short f2bf(float x) {
    unsigned u = __builtin_bit_cast(unsigned, x);
    u = u + 0x7FFFu + ((u >> 16) & 1u);
    return (unsigned short)(u >> 16);
}
static __device__ __forceinline__ float bf2f(unsigned short h) {
    unsigned u = ((unsigned)h) << 16;
    return __builtin_bit_cast(float, u);
}

// ---------------- K0: W -> bf16 hi/lo in B-fragment order ----------------
__global__ __launch_bounds__(256) void cg_prep(const float* __restrict__ mW,
                                               const float* __restrict__ iW,
                                               unsigned short* __restrict__ Wp)
{
    int gid = blockIdx.x * 256 + threadIdx.x;
    int lane = gid & 63;
    int set  = gid >> 6;                            // 1280 sets
    int spl = set & 1;
    int ks  = (set >> 1) & 3;
    int ct  = (set >> 3) & 7;
    int l   = (set >> 6) & 3;
    int mi  = set >> 8;                             // 0..4
    const float* src = (mi < 3) ? (mW + ((size_t)mi * 4 + l) * (KCH * KCH))
                                : (iW + ((size_t)(mi - 3) * 4 + l) * (KCH * KCH));
    int j  = ct * 16 + (lane & 15);
    int kb = ks * 32 + (lane >> 4) * 8;
    unsigned short o[8];
#pragma unroll
    for (int e = 0; e < 8; ++e) {
        float w = src[(size_t)(kb + e) * KCH + j];
        unsigned short h = f2bf(w);
        o[e] = spl ? f2bf(w - bf2f(h)) : h;
    }
    uint4 pk;
    unsigned* pw = (unsigned*)&pk;
#pragma unroll
    for (int q = 0; q < 4; ++q) pw[q] = (unsigned)o[2*q] | ((unsigned)o[2*q+1] << 16);
    *(uint4*)(Wp + (size_t)set * 512 + lane * 8) = pk;
}

// ---------------- K1: U -> G (pair-GEMM B operand) hi/lo in fragment order ----------------
__global__ __launch_bounds__(256) void cg_prepg(const float* __restrict__ U,
                                                unsigned short* __restrict__ Bg)
{
    const int gid  = blockIdx.x * 256 + threadIdx.x;   // 0..1023
    const int s    = gid >> 7;                         // k-step 0..7
    const int spl  = (gid >> 6) & 1;
    const int lane = gid & 63;
    const int c    = lane & 15;
    const int kb   = s * 32 + (lane >> 4) * 8;
    const int Lo   = PR_L[c], cm = PR_M[c];
    unsigned short o[8];
#pragma unroll
    for (int e = 0; e < 8; ++e) {
        const int k  = kb + e;
        const int i  = k >> 4, j = k & 15;
        const int l1 = PR_L[i], a = PR_M[i];
        const int l2 = PR_L[j], b = PR_M[j];
        const int p  = PIDX[Lo][l1][l2];
        float val = (p >= 0) ? U[p * 343 + (a * 7 + b) * 7 + cm] : 0.0f;
        unsigned short h = f2bf(val);
        o[e] = spl ? f2bf(val - bf2f(h)) : h;
    }
    uint4 pk;
    unsigned* pw = (unsigned*)&pk;
#pragma unroll
    for (int q = 0; q < 4; ++q) pw[q] = (unsigned)o[2*q] | ((unsigned)o[2*q+1] << 16);
    *(uint4*)(Bg + (size_t)((s * 2 + spl) * 64 + lane) * 8) = pk;
}

// A-fragment read from bf16 plane [256 rows][128], chunk-XOR swizzled by (key&7)
static __device__ __forceinline__ bf16x8 ldF(const unsigned short* P, int row16, int key, int c) {
    int cs = c ^ (key & 7);
    return *(const bf16x8*)(P + row16 * 128 + cs * 8);
}

// ---------------- K2: three mixer GEMMs, rows = samples (straight-line) ----------------
__global__ __launch_bounds__(512, 2) void cg_mix3(const float* __restrict__ feats,
                                                  const bf16x8* __restrict__ Wp,
                                                  float* __restrict__ P0,
                                                  float* __restrict__ P1,
                                                  float* __restrict__ P2,
                                                  int base)
{
    extern __shared__ char smem[];
    unsigned short* Fh = (unsigned short*)smem;            // 64 KB: [256 rows][128]
    unsigned short* Fl = Fh + 32768;                       // 64 KB

    const int tid  = threadIdx.x;
    const int lane = tid & 63;
    const int ct   = tid >> 6;              // wave id = j col-tile
    const int nl0  = blockIdx.x * 16;       // chunk-local sample base

    {
        const int row = tid >> 1;           // 0..255 = r*16 + nlr
        const int r   = row >> 4;
        const int nlr = row & 15;
        const int kh  = tid & 1;
        const int l = PR_L[r], m = PR_M[r];
        const float* g = feats + (((size_t)l * NSAMP + (base + nl0 + nlr)) * MDIM + m) * KCH + kh * 64;
        unsigned short* fh = Fh + row * 128;
        unsigned short* fl = Fl + row * 128;
#pragma unroll
        for (int c8 = 0; c8 < 8; ++c8) {
            f32x4 a = *(const f32x4*)(g + c8 * 8);
            f32x4 b = *(const f32x4*)(g + c8 * 8 + 4);
            float v[8] = {a[0], a[1], a[2], a[3], b[0], b[1], b[2], b[3]};
            unsigned short hi[8], lo[8];
#pragma unroll
            for (int i = 0; i < 8; ++i) {
                hi[i] = f2bf(v[i]);
                lo[i] = f2bf(v[i] - bf2f(hi[i]));
            }
            uint4 ph, pl;
            unsigned* pwh = (unsigned*)&ph;
            unsigned* pwl = (unsigned*)&pl;
#pragma unroll
            for (int q = 0; q < 4; ++q) {
                pwh[q] = (unsigned)hi[2*q] | ((unsigned)hi[2*q+1] << 16);
                pwl[q] = (unsigned)lo[2*q] | ((unsigned)lo[2*q+1] << 16);
            }
            const int cs = (kh * 8 + c8) ^ (nlr & 7);
            *(uint4*)(fh + cs * 8) = ph;
            *(uint4*)(fl + cs * 8) = pl;
        }
    }
    __syncthreads();

    const int kg = lane >> 4;
    const int l15 = lane & 15;
    const int j = ct * 16 + l15;

    // ---- dual sweep: mi = 0 and 1 ----
    f32x4 acc0[16], acc1[16];
#pragma unroll
    for (int r = 0; r < 16; ++r) {
        acc0[r][0]=acc0[r][1]=acc0[r][2]=acc0[r][3]=0.0f;
        acc1[r][0]=acc1[r][1]=acc1[r][2]=acc1[r][3]=0.0f;
    }
#pragma unroll
    for (int ks = 0; ks < 4; ++ks) {
#pragma unroll
        for (int l = 0; l < 4; ++l) {
            const int s0 = (((0 * 4 + l) * 8 + ct) * 4 + ks) * 2;
            const int s1 = (((1 * 4 + l) * 8 + ct) * 4 + ks) * 2;
            bf16x8 b0h = Wp[(size_t)s0 * 64 + lane];
            bf16x8 b0l = Wp[(size_t)(s0 + 1) * 64 + lane];
            bf16x8 b1h = Wp[(size_t)s1 * 64 + lane];
            bf16x8 b1l = Wp[(size_t)(s1 + 1) * 64 + lane];
#pragma unroll
            for (int r = RB[l]; r < RE[l]; ++r) {
                bf16x8 ah = ldF(Fh, r * 16 + l15, l15, ks * 4 + kg);
                bf16x8 al = ldF(Fl, r * 16 + l15, l15, ks * 4 + kg);
                acc0[r] = __builtin_amdgcn_mfma_f32_16x16x32_bf16(ah, b0h, acc0[r], 0, 0, 0);
                acc0[r] = __builtin_amdgcn_mfma_f32_16x16x32_bf16(ah, b0l, acc0[r], 0, 0, 0);
                acc0[r] = __builtin_amdgcn_mfma_f32_16x16x32_bf16(al, b0h, acc0[r], 0, 0, 0);
                acc1[r] = __builtin_amdgcn_mfma_f32_16x16x32_bf16(ah, b1h, acc1[r], 0, 0, 0);
                acc1[r] = __builtin_amdgcn_mfma_f32_16x16x32_bf16(ah, b1l, acc1[r], 0, 0, 0);
                acc1[r] = __builtin_amdgcn_mfma_f32_16x16x32_bf16(al, b1h, acc1[r], 0, 0, 0);
            }
        }
    }
#pragma unroll
    for (int r = 0; r < 16; ++r) {
#pragma unroll
        for (int q = 0; q < 4; ++q) {
            const int nl = nl0 + (lane >> 4) * 4 + q;
            P0[((size_t)nl * 16 + r) * KCH + j] = acc0[r][q];
            P1[((size_t)nl * 16 + r) * KCH + j] = acc1[r][q];
        }
    }

    // ---- single sweep: mi = 2 ----
#pragma unroll
    for (int r = 0; r < 16; ++r) { acc0[r][0]=acc0[r][1]=acc0[r][2]=acc0[r][3]=0.0f; }
#pragma unroll
    for (int ks = 0; ks < 4; ++ks) {
#pragma unroll
        for (int l = 0; l < 4; ++l) {
            const int s0 = (((2 * 4 + l) * 8 + ct) * 4 + ks) * 2;
            bf16x8 bh = Wp[(size_t)s0 * 64 + lane];
            bf16x8 bl = Wp[(size_t)(s0 + 1) * 64 + lane];
#pragma unroll
            for (int r = RB[l]; r < RE[l]; ++r) {
                bf16x8 ah = ldF(Fh, r * 16 + l15, l15, ks * 4 + kg);
                bf16x8 al = ldF(Fl, r * 16 + l15, l15, ks * 4 + kg);
                acc0[r] = __builtin_amdgcn_mfma_f32_16x16x32_bf16(ah, bh, acc0[r], 0, 0, 0);
                acc0[r] = __builtin_amdgcn_mfma_f32_16x16x32_bf16(ah, bl, acc0[r], 0, 0, 0);
                acc0[r] = __builtin_amdgcn_mfma_f32_16x16x32_bf16(al, bh, acc0[r], 0, 0, 0);
            }
        }
    }
#pragma unroll
    for (int r = 0; r < 16; ++r) {
#pragma unroll
        for (int q = 0; q < 4; ++q) {
            const int nl = nl0 + (lane >> 4) * 4 + q;
            P2[((size_t)nl * 16 + r) * KCH + j] = acc0[r][q];
        }
    }
}

// ---------------- K3: tensor product as pair-GEMM (MFMA) ----------------
// tv[c] = sum_{i,j} cv[i]*mv[j]*G[c,i,j]; A = on-the-fly outer products (hi/lo),
// B = G in fragment order (hi/lo), K = 256 pairs = 8 MFMA k-steps.
__global__ __launch_bounds__(256, 2) void cg_tpg(const float* __restrict__ Pc,
                                                 const float* __restrict__ Pm,
                                                 const bf16x8* __restrict__ Bg,
                                                 float* __restrict__ Pt)
{
    const int tid  = threadIdx.x;
    const int lane = tid & 63;
    const int n    = blockIdx.x >> 1;
    const int ct   = (blockIdx.x & 1) * 4 + (tid >> 6);   // 0..7 col-tile of channels
    const int r    = lane & 15;
    const int kg   = lane >> 4;
    const int ch   = ct * 16 + r;
    const int i0   = kg >> 1;
    const int j0   = (kg & 1) * 8;

    const float* pc = Pc + (size_t)n * 2048 + ch;   // [16 rows][128 ch]
    const float* pm = Pm + (size_t)n * 2048 + ch;

    float cvv[8], mvv[8];
#pragma unroll
    for (int e = 0; e < 8; ++e) {
        cvv[e] = pc[(size_t)(i0 + 2 * e) * KCH];    // cv[i = i0 + 2*step]
        mvv[e] = pm[(size_t)(j0 + e) * KCH];        // mv[j = j0 + e]
    }

    f32x4 acc = {0.0f, 0.0f, 0.0f, 0.0f};
#pragma unroll
    for (int s = 0; s < 8; ++s) {
        float pf[8];
#pragma unroll
        for (int e = 0; e < 8; ++e) pf[e] = cvv[s] * mvv[e];
        unsigned ah[4], al[4];
#pragma unroll
        for (int d = 0; d < 4; ++d) {
            unsigned rh;
            asm("v_cvt_pk_bf16_f32 %0, %1, %2" : "=v"(rh) : "v"(pf[2*d]), "v"(pf[2*d+1]));
            const float h0 = __builtin_bit_cast(float, rh << 16);
            const float h1 = __builtin_bit_cast(float, rh & 0xFFFF0000u);
            const float l0 = pf[2*d]     - h0;
            const float l1 = pf[2*d + 1] - h1;
            unsigned rl;
            asm("v_cvt_pk_bf16_f32 %0, %1, %2" : "=v"(rl) : "v"(l0), "v"(l1));
            ah[d] = rh; al[d] = rl;
        }
        const u32x4 AH = {ah[0], ah[1], ah[2], ah[3]};
        const u32x4 AL = {al[0], al[1], al[2], al[3]};
        const bf16x8 a_h = __builtin_bit_cast(bf16x8, AH);
        const bf16x8 a_l = __builtin_bit_cast(bf16x8, AL);
        const bf16x8 bh = Bg[(size_t)(s * 2 + 0) * 64 + lane];
        const bf16x8 bl = Bg[(size_t)(s * 2 + 1) * 64 + lane];
        acc = __builtin_amdgcn_mfma_f32_16x16x32_bf16(a_h, bh, acc, 0, 0, 0);
        acc = __builtin_amdgcn_mfma_f32_16x16x32_bf16(a_h, bl, acc, 0, 0, 0);
        acc = __builtin_amdgcn_mfma_f32_16x16x32_bf16(a_l, bh, acc, 0, 0, 0);
    }

    // D[row=ch][col=c]: col=lane&15, row=(lane>>4)*4+q
    const int c   = lane & 15;
    const int ch0 = ct * 16 + kg * 4;
    *(f32x4*)(Pt + (size_t)n * 2048 + (size_t)c * KCH + ch0) = acc;
}

// ---------------- K4: iter mix + residual (T=0 -> Pout, T=1 -> final out) ----------------
template<int T>
__global__ __launch_bounds__(512, 2) void cg_iter(const float* __restrict__ Pt,
                                                  const bf16x8* __restrict__ Wp,
                                                  const float* __restrict__ Pres,
                                                  float* __restrict__ Pout,
                                                  float* __restrict__ gout,
                                                  int base)
{
    extern __shared__ char smem[];
    unsigned short* Th = (unsigned short*)smem;   // 64 KB: [256 rows][128]
    unsigned short* Tl = Th + 32768;              // 64 KB

    const int tid  = threadIdx.x;
    const int lane = tid & 63;
    const int ct   = tid >> 6;
    const int nl0  = blockIdx.x * 16;

    // ---- stage tp (f32, linear) -> hi/lo bf16 LDS, XOR-swizzled ----
    {
        const int row = tid >> 1;           // 0..255 = nl*16 + r
        const int kh  = tid & 1;
        const float* g = Pt + ((size_t)(nl0 * 16) + row) * KCH + kh * 64;
        unsigned short* fh = Th + row * 128;
        unsigned short* fl = Tl + row * 128;
        const int key = (row >> 4) & 7;
#pragma unroll
        for (int c8 = 0; c8 < 8; ++c8) {
            f32x4 a = *(const f32x4*)(g + c8 * 8);
            f32x4 b = *(const f32x4*)(g + c8 * 8 + 4);
            float v[8] = {a[0], a[1], a[2], a[3], b[0], b[1], b[2], b[3]};
            unsigned short hi[8], lo[8];
#pragma unroll
            for (int i = 0; i < 8; ++i) {
                hi[i] = f2bf(v[i]);
                lo[i] = f2bf(v[i] - bf2f(hi[i]));
            }
            uint4 ph, pl;
            unsigned* pwh = (unsigned*)&ph;
            unsigned* pwl = (unsigned*)&pl;
#pragma unroll
            for (int q = 0; q < 4; ++q) {
                pwh[q] = (unsigned)hi[2*q] | ((unsigned)hi[2*q+1] << 16);
                pwl[q] = (unsigned)lo[2*q] | ((unsigned)lo[2*q+1] << 16);
            }
            const int cs = (kh * 8 + c8) ^ key;
            *(uint4*)(fh + cs * 8) = ph;
            *(uint4*)(fl + cs * 8) = pl;
        }
    }
    __syncthreads();

    const int kg = lane >> 4;
    const int l15 = lane & 15;
    const int j = ct * 16 + l15;

    f32x4 acc[16];
#pragma unroll
    for (int r = 0; r < 16; ++r) { acc[r][0]=acc[r][1]=acc[r][2]=acc[r][3]=0.0f; }

#pragma unroll
    for (int ks = 0; ks < 4; ++ks) {
#pragma unroll
        for (int l = 0; l < 4; ++l) {
            const int s0 = ((((3 + T) * 4 + l) * 8 + ct) * 4 + ks) * 2;
            bf16x8 bh = Wp[(size_t)s0 * 64 + lane];
            bf16x8 bl = Wp[(size_t)(s0 + 1) * 64 + lane];
#pragma unroll
            for (int r = RB[l]; r < RE[l]; ++r) {
                bf16x8 ah = ldF(Th, l15 * 16 + r, l15, ks * 4 + kg);
                bf16x8 al = ldF(Tl, l15 * 16 + r, l15, ks * 4 + kg);
                acc[r] = __builtin_amdgcn_mfma_f32_16x16x32_bf16(ah, bh, acc[r], 0, 0, 0);
                acc[r] = __builtin_amdgcn_mfma_f32_16x16x32_bf16(ah, bl, acc[r], 0, 0, 0);
                acc[r] = __builtin_amdgcn_mfma_f32_16x16x32_bf16(al, bh, acc[r], 0, 0, 0);
            }
        }
    }

#pragma unroll
    for (int r = 0; r < 16; ++r) {
#pragma unroll
        for (int q = 0; q < 4; ++q) {
            const int nl = nl0 + (lane >> 4) * 4 + q;
            const float val = acc[r][q] + Pres[((size_t)nl * 16 + r) * KCH + j];
            if (T == 0) {
                Pout[((size_t)nl * 16 + r) * KCH + j] = val;
            } else {
                const int n = base + nl;
                gout[(((size_t)PR_L[r] * NSAMP + n) * MDIM + PR_M[r]) * KCH + j] = val;
            }
        }
    }

    if (T == 1) {
        const int j2 = tid & 127;
        const int g  = tid >> 7;     // 0..3
#pragma unroll
        for (int z = 0; z < 12; ++z) {
#pragma unroll
            for (int i = 0; i < 4; ++i) {
                const int n = base + nl0 + g * 4 + i;
                gout[(((size_t)ZL[z] * NSAMP + n) * MDIM + ZM[z]) * KCH + j2] = 0.0f;
            }
        }
    }
}

extern "C" void kernel_launch(void* const* d_in, const int* in_sizes, int n_in,
                              void* d_out, int out_size, void* d_ws, size_t ws_size,
                              hipStream_t stream)
{
    const float* feats = (const float*)d_in[0];
    const float* U     = (const float*)d_in[1];
    const float* mW    = (const float*)d_in[2];
    const float* iW    = (const float*)d_in[3];
    float* out = (float*)d_out;

    const size_t fixed = (size_t)WP_BYTES + BG_BYTES;
    size_t avail = (ws_size > fixed) ? (ws_size - fixed) : 0;
    int NC = (int)(avail / 32768);            // per-sample: P0,P1,P2,Pt = 4*8192 B
    NC = (NC / 16) * 16;
    if (NC > NSAMP) NC = NSAMP;
    if (NC < 16) return;

    char* wsb = (char*)d_ws;
    unsigned short* Wp = (unsigned short*)wsb;
    unsigned short* Bg = (unsigned short*)(wsb + WP_BYTES);
    float* P0 = (float*)(wsb + fixed);
    float* P1 = P0 + (size_t)NC * 2048;
    float* P2 = P1 + (size_t)NC * 2048;
    float* Pt = P2 + (size_t)NC * 2048;

    hipFuncSetAttribute(reinterpret_cast<const void*>(cg_mix3),
                        hipFuncAttributeMaxDynamicSharedMemorySize, 131072);
    hipFuncSetAttribute(reinterpret_cast<const void*>(cg_iter<0>),
                        hipFuncAttributeMaxDynamicSharedMemorySize, 131072);
    hipFuncSetAttribute(reinterpret_cast<const void*>(cg_iter<1>),
                        hipFuncAttributeMaxDynamicSharedMemorySize, 131072);

    cg_prep<<<320, 256, 0, stream>>>(mW, iW, Wp);
    cg_prepg<<<4, 256, 0, stream>>>(U, Bg);

    for (int base = 0; base < NSAMP; base += NC) {
        const int nc = (NSAMP - base < NC) ? (NSAMP - base) : NC;
        cg_mix3<<<nc / 16, 512, 131072, stream>>>(feats, (const bf16x8*)Wp, P0, P1, P2, base);
        // tp = TP(P0, P1); cur1 = P0 + mix(tp, iW0) -> overwrite P1
        cg_tpg<<<nc * 2, 256, 0, stream>>>(P0, P1, (const bf16x8*)Bg, Pt);
        cg_iter<0><<<nc / 16, 512, 131072, stream>>>(Pt, (const bf16x8*)Wp, P0, P1, nullptr, base);
        // tp = TP(P1, P2); out = P1 + mix(tp, iW1)
        cg_tpg<<<nc * 2, 256, 0, stream>>>(P1, P2, (const bf16x8*)Bg, Pt);
        cg_iter<1><<<nc / 16, 512, 131072, stream>>>(Pt, (const bf16x8*)Wp, P1, nullptr, out, base);
    }
}

// Round 10
// 145.665 us; speedup vs baseline: 5.6698x; 1.0588x over previous
//
#include <hip/hip_runtime.h>

#define NSAMP 4096
#define KCH   128
#define MDIM  7

typedef __attribute__((ext_vector_type(8))) short bf16x8;
typedef __attribute__((ext_vector_type(4))) float f32x4;
typedef __attribute__((ext_vector_type(4))) unsigned u32x4;

static constexpr int RB[4] = {0, 1, 4, 9};
static constexpr int RE[4] = {1, 4, 9, 16};
static constexpr int PR_L[16] = {0,1,1,1,2,2,2,2,2,3,3,3,3,3,3,3};
static constexpr int PR_M[16] = {0,0,1,2,0,1,2,3,4,0,1,2,3,4,5,6};

// path index by (L, l1, l2); -1 = no path  (Python enumeration order)
static constexpr int PIDX[4][4][4] = {
  { { 0,-1,-1,-1},{-1, 1,-1,-1},{-1,-1, 2,-1},{-1,-1,-1, 3} },
  { {-1, 4,-1,-1},{ 5, 6, 7,-1},{-1, 8, 9,10},{-1,-1,11,12} },
  { {-1,-1,13,-1},{-1,14,15,16},{17,18,19,20},{-1,21,22,23} },
  { {-1,-1,-1,24},{-1,-1,25,26},{-1,27,28,29},{30,31,32,33} }
};

// invalid (l,m) rows for zero-fill
static constexpr int ZL[12] = {0,0,0,0,0,0, 1,1,1,1, 2,2};
static constexpr int ZM[12] = {1,2,3,4,5,6, 3,4,5,6, 5,6};

#define WP_BYTES 1310720u   // 1280 sets * 512 shorts * 2B
#define BG_BYTES 16384u     // G matrix: 8 steps * 2(hi/lo) * 64 lanes * 8 bf16

static __device__ __forceinline__ unsigned short f2bf(float x) {
    unsigned u = __builtin_bit_cast(unsigned, x);
    u = u + 0x7FFFu + ((u >> 16) & 1u);
    return (unsigned short)(u >> 16);
}
static __device__ __forceinline__ float bf2f(unsigned short h) {
    unsigned u = ((unsigned)h) << 16;
    return __builtin_bit_cast(float, u);
}

// ---------------- K0: W -> bf16 hi/lo in B-fragment order ----------------
__global__ __launch_bounds__(256) void cg_prep(const float* __restrict__ mW,
                                               const float* __restrict__ iW,
                                               unsigned short* __restrict__ Wp)
{
    int gid = blockIdx.x * 256 + threadIdx.x;
    int lane = gid & 63;
    int set  = gid >> 6;                            // 1280 sets
    int spl = set & 1;
    int ks  = (set >> 1) & 3;
    int ct  = (set >> 3) & 7;
    int l   = (set >> 6) & 3;
    int mi  = set >> 8;                             // 0..4
    const float* src = (mi < 3) ? (mW + ((size_t)mi * 4 + l) * (KCH * KCH))
                                : (iW + ((size_t)(mi - 3) * 4 + l) * (KCH * KCH));
    int j  = ct * 16 + (lane & 15);
    int kb = ks * 32 + (lane >> 4) * 8;
    unsigned short o[8];
#pragma unroll
    for (int e = 0; e < 8; ++e) {
        float w = src[(size_t)(kb + e) * KCH + j];
        unsigned short h = f2bf(w);
        o[e] = spl ? f2bf(w - bf2f(h)) : h;
    }
    uint4 pk;
    unsigned* pw = (unsigned*)&pk;
#pragma unroll
    for (int q = 0; q < 4; ++q) pw[q] = (unsigned)o[2*q] | ((unsigned)o[2*q+1] << 16);
    *(uint4*)(Wp + (size_t)set * 512 + lane * 8) = pk;
}

// ---------------- K1: U -> G (pair-GEMM B operand) hi/lo in fragment order ----------------
__global__ __launch_bounds__(256) void cg_prepg(const float* __restrict__ U,
                                                unsigned short* __restrict__ Bg)
{
    const int gid  = blockIdx.x * 256 + threadIdx.x;   // 0..1023
    const int s    = gid >> 7;                         // k-step 0..7
    const int spl  = (gid >> 6) & 1;
    const int lane = gid & 63;
    const int c    = lane & 15;
    const int kb   = s * 32 + (lane >> 4) * 8;
    const int Lo   = PR_L[c], cm = PR_M[c];
    unsigned short o[8];
#pragma unroll
    for (int e = 0; e < 8; ++e) {
        const int k  = kb + e;
        const int i  = k >> 4, j = k & 15;
        const int l1 = PR_L[i], a = PR_M[i];
        const int l2 = PR_L[j], b = PR_M[j];
        const int p  = PIDX[Lo][l1][l2];
        float val = (p >= 0) ? U[p * 343 + (a * 7 + b) * 7 + cm] : 0.0f;
        unsigned short h = f2bf(val);
        o[e] = spl ? f2bf(val - bf2f(h)) : h;
    }
    uint4 pk;
    unsigned* pw = (unsigned*)&pk;
#pragma unroll
    for (int q = 0; q < 4; ++q) pw[q] = (unsigned)o[2*q] | ((unsigned)o[2*q+1] << 16);
    *(uint4*)(Bg + (size_t)((s * 2 + spl) * 64 + lane) * 8) = pk;
}

// A-fragment read from bf16 plane [256 rows][128], chunk-XOR swizzled by (key&7)
static __device__ __forceinline__ bf16x8 ldF(const unsigned short* P, int row16, int key, int c) {
    int cs = c ^ (key & 7);
    return *(const bf16x8*)(P + row16 * 128 + cs * 8);
}

// ---------------- K2: three mixer GEMMs, rows = samples (straight-line) ----------------
__global__ __launch_bounds__(512, 2) void cg_mix3(const float* __restrict__ feats,
                                                  const bf16x8* __restrict__ Wp,
                                                  float* __restrict__ P0,
                                                  float* __restrict__ P1,
                                                  float* __restrict__ P2,
                                                  int base)
{
    extern __shared__ char smem[];
    unsigned short* Fh = (unsigned short*)smem;            // 64 KB: [256 rows][128]
    unsigned short* Fl = Fh + 32768;                       // 64 KB

    const int tid  = threadIdx.x;
    const int lane = tid & 63;
    const int ct   = tid >> 6;              // wave id = j col-tile
    const int nl0  = blockIdx.x * 16;       // chunk-local sample base

    {
        const int row = tid >> 1;           // 0..255 = r*16 + nlr
        const int r   = row >> 4;
        const int nlr = row & 15;
        const int kh  = tid & 1;
        const int l = PR_L[r], m = PR_M[r];
        const float* g = feats + (((size_t)l * NSAMP + (base + nl0 + nlr)) * MDIM + m) * KCH + kh * 64;
        unsigned short* fh = Fh + row * 128;
        unsigned short* fl = Fl + row * 128;
#pragma unroll
        for (int c8 = 0; c8 < 8; ++c8) {
            f32x4 a = *(const f32x4*)(g + c8 * 8);
            f32x4 b = *(const f32x4*)(g + c8 * 8 + 4);
            float v[8] = {a[0], a[1], a[2], a[3], b[0], b[1], b[2], b[3]};
            unsigned short hi[8], lo[8];
#pragma unroll
            for (int i = 0; i < 8; ++i) {
                hi[i] = f2bf(v[i]);
                lo[i] = f2bf(v[i] - bf2f(hi[i]));
            }
            uint4 ph, pl;
            unsigned* pwh = (unsigned*)&ph;
            unsigned* pwl = (unsigned*)&pl;
#pragma unroll
            for (int q = 0; q < 4; ++q) {
                pwh[q] = (unsigned)hi[2*q] | ((unsigned)hi[2*q+1] << 16);
                pwl[q] = (unsigned)lo[2*q] | ((unsigned)lo[2*q+1] << 16);
            }
            const int cs = (kh * 8 + c8) ^ (nlr & 7);
            *(uint4*)(fh + cs * 8) = ph;
            *(uint4*)(fl + cs * 8) = pl;
        }
    }
    __syncthreads();

    const int kg = lane >> 4;
    const int l15 = lane & 15;
    const int j = ct * 16 + l15;

    // ---- dual sweep: mi = 0 and 1 ----
    f32x4 acc0[16], acc1[16];
#pragma unroll
    for (int r = 0; r < 16; ++r) {
        acc0[r][0]=acc0[r][1]=acc0[r][2]=acc0[r][3]=0.0f;
        acc1[r][0]=acc1[r][1]=acc1[r][2]=acc1[r][3]=0.0f;
    }
#pragma unroll
    for (int ks = 0; ks < 4; ++ks) {
#pragma unroll
        for (int l = 0; l < 4; ++l) {
            const int s0 = (((0 * 4 + l) * 8 + ct) * 4 + ks) * 2;
            const int s1 = (((1 * 4 + l) * 8 + ct) * 4 + ks) * 2;
            bf16x8 b0h = Wp[(size_t)s0 * 64 + lane];
            bf16x8 b0l = Wp[(size_t)(s0 + 1) * 64 + lane];
            bf16x8 b1h = Wp[(size_t)s1 * 64 + lane];
            bf16x8 b1l = Wp[(size_t)(s1 + 1) * 64 + lane];
#pragma unroll
            for (int r = RB[l]; r < RE[l]; ++r) {
                bf16x8 ah = ldF(Fh, r * 16 + l15, l15, ks * 4 + kg);
                bf16x8 al = ldF(Fl, r * 16 + l15, l15, ks * 4 + kg);
                acc0[r] = __builtin_amdgcn_mfma_f32_16x16x32_bf16(ah, b0h, acc0[r], 0, 0, 0);
                acc0[r] = __builtin_amdgcn_mfma_f32_16x16x32_bf16(ah, b0l, acc0[r], 0, 0, 0);
                acc0[r] = __builtin_amdgcn_mfma_f32_16x16x32_bf16(al, b0h, acc0[r], 0, 0, 0);
                acc1[r] = __builtin_amdgcn_mfma_f32_16x16x32_bf16(ah, b1h, acc1[r], 0, 0, 0);
                acc1[r] = __builtin_amdgcn_mfma_f32_16x16x32_bf16(ah, b1l, acc1[r], 0, 0, 0);
                acc1[r] = __builtin_amdgcn_mfma_f32_16x16x32_bf16(al, b1h, acc1[r], 0, 0, 0);
            }
        }
    }
#pragma unroll
    for (int r = 0; r < 16; ++r) {
#pragma unroll
        for (int q = 0; q < 4; ++q) {
            const int nl = nl0 + (lane >> 4) * 4 + q;
            P0[((size_t)nl * 16 + r) * KCH + j] = acc0[r][q];
            P1[((size_t)nl * 16 + r) * KCH + j] = acc1[r][q];
        }
    }

    // ---- single sweep: mi = 2 ----
#pragma unroll
    for (int r = 0; r < 16; ++r) { acc0[r][0]=acc0[r][1]=acc0[r][2]=acc0[r][3]=0.0f; }
#pragma unroll
    for (int ks = 0; ks < 4; ++ks) {
#pragma unroll
        for (int l = 0; l < 4; ++l) {
            const int s0 = (((2 * 4 + l) * 8 + ct) * 4 + ks) * 2;
            bf16x8 bh = Wp[(size_t)s0 * 64 + lane];
            bf16x8 bl = Wp[(size_t)(s0 + 1) * 64 + lane];
#pragma unroll
            for (int r = RB[l]; r < RE[l]; ++r) {
                bf16x8 ah = ldF(Fh, r * 16 + l15, l15, ks * 4 + kg);
                bf16x8 al = ldF(Fl, r * 16 + l15, l15, ks * 4 + kg);
                acc0[r] = __builtin_amdgcn_mfma_f32_16x16x32_bf16(ah, bh, acc0[r], 0, 0, 0);
                acc0[r] = __builtin_amdgcn_mfma_f32_16x16x32_bf16(ah, bl, acc0[r], 0, 0, 0);
                acc0[r] = __builtin_amdgcn_mfma_f32_16x16x32_bf16(al, bh, acc0[r], 0, 0, 0);
            }
        }
    }
#pragma unroll
    for (int r = 0; r < 16; ++r) {
#pragma unroll
        for (int q = 0; q < 4; ++q) {
            const int nl = nl0 + (lane >> 4) * 4 + q;
            P2[((size_t)nl * 16 + r) * KCH + j] = acc0[r][q];
        }
    }
}

// ---------------- K3: fused TP-GEMM + iter mix + residual ----------------
// Phase 1: per wave, 16 TP units (sample n_local, channel-tile = wave id) via
//          MFMA pair-GEMM; acc -> hi/lo bf16 packed u32 -> swizzled LDS planes.
// Phase 2: iter MFMA sweep over LDS planes, acc initialized from residual Pc.
// LDS swizzle key = (sample ^ c) so writes (c varies) and reads (sample varies)
// are both bank-spread.
template<int T>
__global__ __launch_bounds__(512) void cg_fiter(const float* __restrict__ Pc,
                                                const float* __restrict__ Pm,
                                                const bf16x8* __restrict__ Bg,
                                                const bf16x8* __restrict__ Wp,
                                                float* __restrict__ Pout,
                                                float* __restrict__ gout,
                                                int base)
{
    extern __shared__ char smem[];
    unsigned short* Th = (unsigned short*)smem;   // 64 KB: [256 rows][128]
    unsigned short* Tl = Th + 32768;              // 64 KB

    const int tid  = threadIdx.x;
    const int lane = tid & 63;
    const int ct   = tid >> 6;            // wave id = channel col-tile
    const int nl0  = blockIdx.x * 16;

    const int kg  = lane >> 4;
    const int l15 = lane & 15;

    // ---- phase 1: TP pair-GEMM, one sample per unit ----
    const int i0 = kg >> 1;
    const int j0 = (kg & 1) * 8;
    const int ch = ct * 16 + l15;         // A-row channel for loads
    // output mapping (per unit): c-row = l15, channels ch0..ch0+3
    const int c_out = l15;
    const int ch0   = ct * 16 + kg * 4;
    const int chunkA = ct * 2 + (kg >> 1);          // (ch0>>3) and ((ch0+2)>>3) share this

#pragma unroll 1
    for (int u = 0; u < 16; ++u) {
        const int n_local = u;
        const float* pc = Pc + ((size_t)(nl0 + n_local) * 16) * KCH + ch;
        const float* pm = Pm + ((size_t)(nl0 + n_local) * 16) * KCH + ch;

        float cvv[8], mvv[8];
#pragma unroll
        for (int e = 0; e < 8; ++e) {
            cvv[e] = pc[(size_t)(i0 + 2 * e) * KCH];
            mvv[e] = pm[(size_t)(j0 + e) * KCH];
        }

        f32x4 acc = {0.0f, 0.0f, 0.0f, 0.0f};
#pragma unroll
        for (int s = 0; s < 8; ++s) {
            float pf[8];
#pragma unroll
            for (int e = 0; e < 8; ++e) pf[e] = cvv[s] * mvv[e];
            unsigned ah[4], al[4];
#pragma unroll
            for (int d = 0; d < 4; ++d) {
                unsigned rh;
                asm("v_cvt_pk_bf16_f32 %0, %1, %2" : "=v"(rh) : "v"(pf[2*d]), "v"(pf[2*d+1]));
                const float h0 = __builtin_bit_cast(float, rh << 16);
                const float h1 = __builtin_bit_cast(float, rh & 0xFFFF0000u);
                const float l0 = pf[2*d]     - h0;
                const float l1 = pf[2*d + 1] - h1;
                unsigned rl;
                asm("v_cvt_pk_bf16_f32 %0, %1, %2" : "=v"(rl) : "v"(l0), "v"(l1));
                ah[d] = rh; al[d] = rl;
            }
            const u32x4 AH = {ah[0], ah[1], ah[2], ah[3]};
            const u32x4 AL = {al[0], al[1], al[2], al[3]};
            const bf16x8 a_h = __builtin_bit_cast(bf16x8, AH);
            const bf16x8 a_l = __builtin_bit_cast(bf16x8, AL);
            const bf16x8 bh = Bg[(size_t)(s * 2 + 0) * 64 + lane];
            const bf16x8 bl = Bg[(size_t)(s * 2 + 1) * 64 + lane];
            acc = __builtin_amdgcn_mfma_f32_16x16x32_bf16(a_h, bh, acc, 0, 0, 0);
            acc = __builtin_amdgcn_mfma_f32_16x16x32_bf16(a_h, bl, acc, 0, 0, 0);
            acc = __builtin_amdgcn_mfma_f32_16x16x32_bf16(a_l, bh, acc, 0, 0, 0);
        }

        // write acc (4 channels of c-row c_out, sample n_local) as hi/lo bf16 to LDS
        const int row16 = n_local * 16 + c_out;
        const int key   = (n_local ^ c_out) & 7;
        const int cs    = chunkA ^ key;
        const int soff  = row16 * 128 + cs * 8 + (ch0 & 7);
        unsigned h01, h23, l01, l23;
        {
            const unsigned short h0 = f2bf(acc[0]);
            const unsigned short h1 = f2bf(acc[1]);
            const unsigned short h2 = f2bf(acc[2]);
            const unsigned short h3 = f2bf(acc[3]);
            h01 = (unsigned)h0 | ((unsigned)h1 << 16);
            h23 = (unsigned)h2 | ((unsigned)h3 << 16);
            const unsigned short q0 = f2bf(acc[0] - bf2f(h0));
            const unsigned short q1 = f2bf(acc[1] - bf2f(h1));
            const unsigned short q2 = f2bf(acc[2] - bf2f(h2));
            const unsigned short q3 = f2bf(acc[3] - bf2f(h3));
            l01 = (unsigned)q0 | ((unsigned)q1 << 16);
            l23 = (unsigned)q2 | ((unsigned)q3 << 16);
        }
        *(unsigned*)(Th + soff)     = h01;
        *(unsigned*)(Th + soff + 2) = h23;
        *(unsigned*)(Tl + soff)     = l01;
        *(unsigned*)(Tl + soff + 2) = l23;
    }
    __syncthreads();

    // ---- phase 2: iter MFMA sweep, acc initialized from residual ----
    const int j = ct * 16 + l15;

    f32x4 acc[16];
#pragma unroll
    for (int r = 0; r < 16; ++r) {
#pragma unroll
        for (int q = 0; q < 4; ++q) {
            const int nl = kg * 4 + q;
            acc[r][q] = Pc[((size_t)(nl0 + nl) * 16 + r) * KCH + j];
        }
    }

#pragma unroll
    for (int ks = 0; ks < 4; ++ks) {
#pragma unroll
        for (int l = 0; l < 4; ++l) {
            const int s0 = ((((3 + T) * 4 + l) * 8 + ct) * 4 + ks) * 2;
            bf16x8 bh = Wp[(size_t)s0 * 64 + lane];
            bf16x8 bl = Wp[(size_t)(s0 + 1) * 64 + lane];
#pragma unroll
            for (int r = RB[l]; r < RE[l]; ++r) {
                // row = sample*16 + c-row; key = sample ^ c-row
                bf16x8 ah = ldF(Th, l15 * 16 + r, l15 ^ r, ks * 4 + kg);
                bf16x8 al = ldF(Tl, l15 * 16 + r, l15 ^ r, ks * 4 + kg);
                acc[r] = __builtin_amdgcn_mfma_f32_16x16x32_bf16(ah, bh, acc[r], 0, 0, 0);
                acc[r] = __builtin_amdgcn_mfma_f32_16x16x32_bf16(ah, bl, acc[r], 0, 0, 0);
                acc[r] = __builtin_amdgcn_mfma_f32_16x16x32_bf16(al, bh, acc[r], 0, 0, 0);
            }
        }
    }

#pragma unroll
    for (int r = 0; r < 16; ++r) {
#pragma unroll
        for (int q = 0; q < 4; ++q) {
            const int nl = nl0 + kg * 4 + q;
            const float val = acc[r][q];
            if (T == 0) {
                Pout[((size_t)nl * 16 + r) * KCH + j] = val;
            } else {
                const int n = base + nl;
                gout[(((size_t)PR_L[r] * NSAMP + n) * MDIM + PR_M[r]) * KCH + j] = val;
            }
        }
    }

    if (T == 1) {
        // zero-fill the 12 invalid (l,m) rows
        const int j2 = tid & 127;
        const int g  = tid >> 7;     // 0..3
#pragma unroll
        for (int z = 0; z < 12; ++z) {
#pragma unroll
            for (int i = 0; i < 4; ++i) {
                const int n = base + nl0 + g * 4 + i;
                gout[(((size_t)ZL[z] * NSAMP + n) * MDIM + ZM[z]) * KCH + j2] = 0.0f;
            }
        }
    }
}

extern "C" void kernel_launch(void* const* d_in, const int* in_sizes, int n_in,
                              void* d_out, int out_size, void* d_ws, size_t ws_size,
                              hipStream_t stream)
{
    const float* feats = (const float*)d_in[0];
    const float* U     = (const float*)d_in[1];
    const float* mW    = (const float*)d_in[2];
    const float* iW    = (const float*)d_in[3];
    float* out = (float*)d_out;

    const size_t fixed = (size_t)WP_BYTES + BG_BYTES;
    size_t avail = (ws_size > fixed) ? (ws_size - fixed) : 0;
    int NC = (int)(avail / 24576);            // per-sample: P0,P1,P2 = 3*8192 B
    NC = (NC / 16) * 16;
    if (NC > NSAMP) NC = NSAMP;
    if (NC < 16) return;

    char* wsb = (char*)d_ws;
    unsigned short* Wp = (unsigned short*)wsb;
    unsigned short* Bg = (unsigned short*)(wsb + WP_BYTES);
    float* P0 = (float*)(wsb + fixed);
    float* P1 = P0 + (size_t)NC * 2048;
    float* P2 = P1 + (size_t)NC * 2048;

    hipFuncSetAttribute(reinterpret_cast<const void*>(cg_mix3),
                        hipFuncAttributeMaxDynamicSharedMemorySize, 131072);
    hipFuncSetAttribute(reinterpret_cast<const void*>(cg_fiter<0>),
                        hipFuncAttributeMaxDynamicSharedMemorySize, 131072);
    hipFuncSetAttribute(reinterpret_cast<const void*>(cg_fiter<1>),
                        hipFuncAttributeMaxDynamicSharedMemorySize, 131072);

    cg_prep<<<320, 256, 0, stream>>>(mW, iW, Wp);
    cg_prepg<<<4, 256, 0, stream>>>(U, Bg);

    for (int base = 0; base < NSAMP; base += NC) {
        const int nc = (NSAMP - base < NC) ? (NSAMP - base) : NC;
        cg_mix3<<<nc / 16, 512, 131072, stream>>>(feats, (const bf16x8*)Wp, P0, P1, P2, base);
        // cur1 = P0 + mix(TP(P0,P1), iW0)  -> overwrite P1
        cg_fiter<0><<<nc / 16, 512, 131072, stream>>>(P0, P1, (const bf16x8*)Bg,
                                                      (const bf16x8*)Wp, P1, nullptr, base);
        // out  = P1 + mix(TP(P1,P2), iW1)
        cg_fiter<1><<<nc / 16, 512, 131072, stream>>>(P1, P2, (const bf16x8*)Bg,
                                                      (const bf16x8*)Wp, nullptr, out, base);
    }
}

// Round 11
// 132.925 us; speedup vs baseline: 6.2132x; 1.0958x over previous
//
#include <hip/hip_runtime.h>

#define NSAMP 4096
#define KCH   128
#define MDIM  7

typedef __attribute__((ext_vector_type(8))) short bf16x8;
typedef __attribute__((ext_vector_type(4))) float f32x4;
typedef __attribute__((ext_vector_type(4))) unsigned u32x4;

static constexpr int RB[4] = {0, 1, 4, 9};
static constexpr int RE[4] = {1, 4, 9, 16};
static constexpr int PR_L[16] = {0,1,1,1,2,2,2,2,2,3,3,3,3,3,3,3};
static constexpr int PR_M[16] = {0,0,1,2,0,1,2,3,4,0,1,2,3,4,5,6};

// path index by (L, l1, l2); -1 = no path  (Python enumeration order)
static constexpr int PIDX[4][4][4] = {
  { { 0,-1,-1,-1},{-1, 1,-1,-1},{-1,-1, 2,-1},{-1,-1,-1, 3} },
  { {-1, 4,-1,-1},{ 5, 6, 7,-1},{-1, 8, 9,10},{-1,-1,11,12} },
  { {-1,-1,13,-1},{-1,14,15,16},{17,18,19,20},{-1,21,22,23} },
  { {-1,-1,-1,24},{-1,-1,25,26},{-1,27,28,29},{30,31,32,33} }
};

// invalid (l,m) rows for zero-fill
static constexpr int ZL[12] = {0,0,0,0,0,0, 1,1,1,1, 2,2};
static constexpr int ZM[12] = {1,2,3,4,5,6, 3,4,5,6, 5,6};

#define WP_BYTES 1310720u   // 1280 sets * 512 shorts * 2B
#define BG_BYTES 16384u     // G matrix: 8 steps * 2(hi/lo) * 64 lanes * 8 bf16

static __device__ __forceinline__ unsigned short f2bf(float x) {
    unsigned u = __builtin_bit_cast(unsigned, x);
    u = u + 0x7FFFu + ((u >> 16) & 1u);
    return (unsigned short)(u >> 16);
}
static __device__ __forceinline__ float bf2f(unsigned short h) {
    unsigned u = ((unsigned)h) << 16;
    return __builtin_bit_cast(float, u);
}

// ---------------- K0: W -> bf16 hi/lo in B-fragment order ----------------
__global__ __launch_bounds__(256) void cg_prep(const float* __restrict__ mW,
                                               const float* __restrict__ iW,
                                               unsigned short* __restrict__ Wp)
{
    int gid = blockIdx.x * 256 + threadIdx.x;
    int lane = gid & 63;
    int set  = gid >> 6;                            // 1280 sets
    int spl = set & 1;
    int ks  = (set >> 1) & 3;
    int ct  = (set >> 3) & 7;
    int l   = (set >> 6) & 3;
    int mi  = set >> 8;                             // 0..4
    const float* src = (mi < 3) ? (mW + ((size_t)mi * 4 + l) * (KCH * KCH))
                                : (iW + ((size_t)(mi - 3) * 4 + l) * (KCH * KCH));
    int j  = ct * 16 + (lane & 15);
    int kb = ks * 32 + (lane >> 4) * 8;
    unsigned short o[8];
#pragma unroll
    for (int e = 0; e < 8; ++e) {
        float w = src[(size_t)(kb + e) * KCH + j];
        unsigned short h = f2bf(w);
        o[e] = spl ? f2bf(w - bf2f(h)) : h;
    }
    uint4 pk;
    unsigned* pw = (unsigned*)&pk;
#pragma unroll
    for (int q = 0; q < 4; ++q) pw[q] = (unsigned)o[2*q] | ((unsigned)o[2*q+1] << 16);
    *(uint4*)(Wp + (size_t)set * 512 + lane * 8) = pk;
}

// ---------------- K1: U -> G (pair-GEMM B operand) hi/lo in fragment order ----------------
__global__ __launch_bounds__(256) void cg_prepg(const float* __restrict__ U,
                                                unsigned short* __restrict__ Bg)
{
    const int gid  = blockIdx.x * 256 + threadIdx.x;   // 0..1023
    const int s    = gid >> 7;                         // k-step 0..7
    const int spl  = (gid >> 6) & 1;
    const int lane = gid & 63;
    const int c    = lane & 15;
    const int kb   = s * 32 + (lane >> 4) * 8;
    const int Lo   = PR_L[c], cm = PR_M[c];
    unsigned short o[8];
#pragma unroll
    for (int e = 0; e < 8; ++e) {
        const int k  = kb + e;
        const int i  = k >> 4, j = k & 15;
        const int l1 = PR_L[i], a = PR_M[i];
        const int l2 = PR_L[j], b = PR_M[j];
        const int p  = PIDX[Lo][l1][l2];
        float val = (p >= 0) ? U[p * 343 + (a * 7 + b) * 7 + cm] : 0.0f;
        unsigned short h = f2bf(val);
        o[e] = spl ? f2bf(val - bf2f(h)) : h;
    }
    uint4 pk;
    unsigned* pw = (unsigned*)&pk;
#pragma unroll
    for (int q = 0; q < 4; ++q) pw[q] = (unsigned)o[2*q] | ((unsigned)o[2*q+1] << 16);
    *(uint4*)(Bg + (size_t)((s * 2 + spl) * 64 + lane) * 8) = pk;
}

// A-fragment read from bf16 plane [256 rows][128], chunk-XOR swizzled by (key&7)
static __device__ __forceinline__ bf16x8 ldF(const unsigned short* P, int row16, int key, int c) {
    int cs = c ^ (key & 7);
    return *(const bf16x8*)(P + row16 * 128 + cs * 8);
}

// ---------------- K2: three mixer GEMMs, rows = samples (straight-line) ----------------
__global__ __launch_bounds__(512, 2) void cg_mix3(const float* __restrict__ feats,
                                                  const bf16x8* __restrict__ Wp,
                                                  float* __restrict__ P0,
                                                  float* __restrict__ P1,
                                                  float* __restrict__ P2,
                                                  int base)
{
    extern __shared__ char smem[];
    unsigned short* Fh = (unsigned short*)smem;            // 64 KB: [256 rows][128]
    unsigned short* Fl = Fh + 32768;                       // 64 KB

    const int tid  = threadIdx.x;
    const int lane = tid & 63;
    const int ct   = tid >> 6;              // wave id = j col-tile
    const int nl0  = blockIdx.x * 16;       // chunk-local sample base

    {
        const int row = tid >> 1;           // 0..255 = r*16 + nlr
        const int r   = row >> 4;
        const int nlr = row & 15;
        const int kh  = tid & 1;
        const int l = PR_L[r], m = PR_M[r];
        const float* g = feats + (((size_t)l * NSAMP + (base + nl0 + nlr)) * MDIM + m) * KCH + kh * 64;
        unsigned short* fh = Fh + row * 128;
        unsigned short* fl = Fl + row * 128;
#pragma unroll
        for (int c8 = 0; c8 < 8; ++c8) {
            f32x4 a = *(const f32x4*)(g + c8 * 8);
            f32x4 b = *(const f32x4*)(g + c8 * 8 + 4);
            float v[8] = {a[0], a[1], a[2], a[3], b[0], b[1], b[2], b[3]};
            unsigned short hi[8], lo[8];
#pragma unroll
            for (int i = 0; i < 8; ++i) {
                hi[i] = f2bf(v[i]);
                lo[i] = f2bf(v[i] - bf2f(hi[i]));
            }
            uint4 ph, pl;
            unsigned* pwh = (unsigned*)&ph;
            unsigned* pwl = (unsigned*)&pl;
#pragma unroll
            for (int q = 0; q < 4; ++q) {
                pwh[q] = (unsigned)hi[2*q] | ((unsigned)hi[2*q+1] << 16);
                pwl[q] = (unsigned)lo[2*q] | ((unsigned)lo[2*q+1] << 16);
            }
            const int cs = (kh * 8 + c8) ^ (nlr & 7);
            *(uint4*)(fh + cs * 8) = ph;
            *(uint4*)(fl + cs * 8) = pl;
        }
    }
    __syncthreads();

    const int kg = lane >> 4;
    const int l15 = lane & 15;
    const int j = ct * 16 + l15;

    // ---- dual sweep: mi = 0 and 1 ----
    f32x4 acc0[16], acc1[16];
#pragma unroll
    for (int r = 0; r < 16; ++r) {
        acc0[r][0]=acc0[r][1]=acc0[r][2]=acc0[r][3]=0.0f;
        acc1[r][0]=acc1[r][1]=acc1[r][2]=acc1[r][3]=0.0f;
    }
#pragma unroll
    for (int ks = 0; ks < 4; ++ks) {
#pragma unroll
        for (int l = 0; l < 4; ++l) {
            const int s0 = (((0 * 4 + l) * 8 + ct) * 4 + ks) * 2;
            const int s1 = (((1 * 4 + l) * 8 + ct) * 4 + ks) * 2;
            bf16x8 b0h = Wp[(size_t)s0 * 64 + lane];
            bf16x8 b0l = Wp[(size_t)(s0 + 1) * 64 + lane];
            bf16x8 b1h = Wp[(size_t)s1 * 64 + lane];
            bf16x8 b1l = Wp[(size_t)(s1 + 1) * 64 + lane];
#pragma unroll
            for (int r = RB[l]; r < RE[l]; ++r) {
                bf16x8 ah = ldF(Fh, r * 16 + l15, l15, ks * 4 + kg);
                bf16x8 al = ldF(Fl, r * 16 + l15, l15, ks * 4 + kg);
                acc0[r] = __builtin_amdgcn_mfma_f32_16x16x32_bf16(ah, b0h, acc0[r], 0, 0, 0);
                acc0[r] = __builtin_amdgcn_mfma_f32_16x16x32_bf16(ah, b0l, acc0[r], 0, 0, 0);
                acc0[r] = __builtin_amdgcn_mfma_f32_16x16x32_bf16(al, b0h, acc0[r], 0, 0, 0);
                acc1[r] = __builtin_amdgcn_mfma_f32_16x16x32_bf16(ah, b1h, acc1[r], 0, 0, 0);
                acc1[r] = __builtin_amdgcn_mfma_f32_16x16x32_bf16(ah, b1l, acc1[r], 0, 0, 0);
                acc1[r] = __builtin_amdgcn_mfma_f32_16x16x32_bf16(al, b1h, acc1[r], 0, 0, 0);
            }
        }
    }
#pragma unroll
    for (int r = 0; r < 16; ++r) {
#pragma unroll
        for (int q = 0; q < 4; ++q) {
            const int nl = nl0 + (lane >> 4) * 4 + q;
            P0[((size_t)nl * 16 + r) * KCH + j] = acc0[r][q];
            P1[((size_t)nl * 16 + r) * KCH + j] = acc1[r][q];
        }
    }

    // ---- single sweep: mi = 2 ----
#pragma unroll
    for (int r = 0; r < 16; ++r) { acc0[r][0]=acc0[r][1]=acc0[r][2]=acc0[r][3]=0.0f; }
#pragma unroll
    for (int ks = 0; ks < 4; ++ks) {
#pragma unroll
        for (int l = 0; l < 4; ++l) {
            const int s0 = (((2 * 4 + l) * 8 + ct) * 4 + ks) * 2;
            bf16x8 bh = Wp[(size_t)s0 * 64 + lane];
            bf16x8 bl = Wp[(size_t)(s0 + 1) * 64 + lane];
#pragma unroll
            for (int r = RB[l]; r < RE[l]; ++r) {
                bf16x8 ah = ldF(Fh, r * 16 + l15, l15, ks * 4 + kg);
                bf16x8 al = ldF(Fl, r * 16 + l15, l15, ks * 4 + kg);
                acc0[r] = __builtin_amdgcn_mfma_f32_16x16x32_bf16(ah, bh, acc0[r], 0, 0, 0);
                acc0[r] = __builtin_amdgcn_mfma_f32_16x16x32_bf16(ah, bl, acc0[r], 0, 0, 0);
                acc0[r] = __builtin_amdgcn_mfma_f32_16x16x32_bf16(al, bh, acc0[r], 0, 0, 0);
            }
        }
    }
#pragma unroll
    for (int r = 0; r < 16; ++r) {
#pragma unroll
        for (int q = 0; q < 4; ++q) {
            const int nl = nl0 + (lane >> 4) * 4 + q;
            P2[((size_t)nl * 16 + r) * KCH + j] = acc0[r][q];
        }
    }
}

// ---------------- K3: fused TP-GEMM + iter mix + residual ----------------
// Phase 1: per wave, 16 TP units via MFMA pair-GEMM; A = single-bf16 products
//          (2 MFMA vs G hi/lo); acc -> single bf16 plane in swizzled LDS.
// Phase 2: iter MFMA sweep (2 MFMA vs W hi/lo), acc initialized from residual.
// LDS = one plane (64 KB) -> 2 blocks/CU.
template<int T>
__global__ __launch_bounds__(512, 4) void cg_fiter(const float* __restrict__ Pc,
                                                   const float* __restrict__ Pm,
                                                   const bf16x8* __restrict__ Bg,
                                                   const bf16x8* __restrict__ Wp,
                                                   float* __restrict__ Pout,
                                                   float* __restrict__ gout,
                                                   int base)
{
    extern __shared__ char smem[];
    unsigned short* Th = (unsigned short*)smem;   // 64 KB: [256 rows][128]

    const int tid  = threadIdx.x;
    const int lane = tid & 63;
    const int ct   = tid >> 6;            // wave id = channel col-tile
    const int nl0  = blockIdx.x * 16;

    const int kg  = lane >> 4;
    const int l15 = lane & 15;

    // ---- phase 1: TP pair-GEMM, one sample per unit ----
    const int i0 = kg >> 1;
    const int j0 = (kg & 1) * 8;
    const int ch = ct * 16 + l15;         // A-row channel for loads
    const int c_out = l15;
    const int ch0   = ct * 16 + kg * 4;
    const int chunkA = ct * 2 + (kg >> 1);

#pragma unroll 1
    for (int u = 0; u < 16; ++u) {
        const int n_local = u;
        const float* pc = Pc + ((size_t)(nl0 + n_local) * 16) * KCH + ch;
        const float* pm = Pm + ((size_t)(nl0 + n_local) * 16) * KCH + ch;

        float cvv[8], mvv[8];
#pragma unroll
        for (int e = 0; e < 8; ++e) {
            cvv[e] = pc[(size_t)(i0 + 2 * e) * KCH];
            mvv[e] = pm[(size_t)(j0 + e) * KCH];
        }

        f32x4 acc = {0.0f, 0.0f, 0.0f, 0.0f};
#pragma unroll
        for (int s = 0; s < 8; ++s) {
            float pf[8];
#pragma unroll
            for (int e = 0; e < 8; ++e) pf[e] = cvv[s] * mvv[e];
            unsigned ah[4];
#pragma unroll
            for (int d = 0; d < 4; ++d) {
                asm("v_cvt_pk_bf16_f32 %0, %1, %2" : "=v"(ah[d]) : "v"(pf[2*d]), "v"(pf[2*d+1]));
            }
            const u32x4 AH = {ah[0], ah[1], ah[2], ah[3]};
            const bf16x8 a_h = __builtin_bit_cast(bf16x8, AH);
            const bf16x8 bh = Bg[(size_t)(s * 2 + 0) * 64 + lane];
            const bf16x8 bl = Bg[(size_t)(s * 2 + 1) * 64 + lane];
            acc = __builtin_amdgcn_mfma_f32_16x16x32_bf16(a_h, bh, acc, 0, 0, 0);
            acc = __builtin_amdgcn_mfma_f32_16x16x32_bf16(a_h, bl, acc, 0, 0, 0);
        }

        // write acc (4 channels of c-row c_out, sample n_local) as bf16 to LDS
        const int row16 = n_local * 16 + c_out;
        const int key   = (n_local ^ c_out) & 7;
        const int cs    = chunkA ^ key;
        const int soff  = row16 * 128 + cs * 8 + (ch0 & 7);
        unsigned h01, h23;
        {
            const unsigned short h0 = f2bf(acc[0]);
            const unsigned short h1 = f2bf(acc[1]);
            const unsigned short h2 = f2bf(acc[2]);
            const unsigned short h3 = f2bf(acc[3]);
            h01 = (unsigned)h0 | ((unsigned)h1 << 16);
            h23 = (unsigned)h2 | ((unsigned)h3 << 16);
        }
        *(unsigned*)(Th + soff)     = h01;
        *(unsigned*)(Th + soff + 2) = h23;
    }
    __syncthreads();

    // ---- phase 2: iter MFMA sweep, acc initialized from residual ----
    const int j = ct * 16 + l15;

    f32x4 acc[16];
#pragma unroll
    for (int r = 0; r < 16; ++r) {
#pragma unroll
        for (int q = 0; q < 4; ++q) {
            const int nl = kg * 4 + q;
            acc[r][q] = Pc[((size_t)(nl0 + nl) * 16 + r) * KCH + j];
        }
    }

#pragma unroll
    for (int ks = 0; ks < 4; ++ks) {
#pragma unroll
        for (int l = 0; l < 4; ++l) {
            const int s0 = ((((3 + T) * 4 + l) * 8 + ct) * 4 + ks) * 2;
            bf16x8 bh = Wp[(size_t)s0 * 64 + lane];
            bf16x8 bl = Wp[(size_t)(s0 + 1) * 64 + lane];
#pragma unroll
            for (int r = RB[l]; r < RE[l]; ++r) {
                // row = sample*16 + c-row; key = sample ^ c-row
                bf16x8 ah = ldF(Th, l15 * 16 + r, l15 ^ r, ks * 4 + kg);
                acc[r] = __builtin_amdgcn_mfma_f32_16x16x32_bf16(ah, bh, acc[r], 0, 0, 0);
                acc[r] = __builtin_amdgcn_mfma_f32_16x16x32_bf16(ah, bl, acc[r], 0, 0, 0);
            }
        }
    }

#pragma unroll
    for (int r = 0; r < 16; ++r) {
#pragma unroll
        for (int q = 0; q < 4; ++q) {
            const int nl = nl0 + kg * 4 + q;
            const float val = acc[r][q];
            if (T == 0) {
                Pout[((size_t)nl * 16 + r) * KCH + j] = val;
            } else {
                const int n = base + nl;
                gout[(((size_t)PR_L[r] * NSAMP + n) * MDIM + PR_M[r]) * KCH + j] = val;
            }
        }
    }

    if (T == 1) {
        // zero-fill the 12 invalid (l,m) rows
        const int j2 = tid & 127;
        const int g  = tid >> 7;     // 0..3
#pragma unroll
        for (int z = 0; z < 12; ++z) {
#pragma unroll
            for (int i = 0; i < 4; ++i) {
                const int n = base + nl0 + g * 4 + i;
                gout[(((size_t)ZL[z] * NSAMP + n) * MDIM + ZM[z]) * KCH + j2] = 0.0f;
            }
        }
    }
}

extern "C" void kernel_launch(void* const* d_in, const int* in_sizes, int n_in,
                              void* d_out, int out_size, void* d_ws, size_t ws_size,
                              hipStream_t stream)
{
    const float* feats = (const float*)d_in[0];
    const float* U     = (const float*)d_in[1];
    const float* mW    = (const float*)d_in[2];
    const float* iW    = (const float*)d_in[3];
    float* out = (float*)d_out;

    const size_t fixed = (size_t)WP_BYTES + BG_BYTES;
    size_t avail = (ws_size > fixed) ? (ws_size - fixed) : 0;
    int NC = (int)(avail / 24576);            // per-sample: P0,P1,P2 = 3*8192 B
    NC = (NC / 16) * 16;
    if (NC > NSAMP) NC = NSAMP;
    if (NC < 16) return;

    char* wsb = (char*)d_ws;
    unsigned short* Wp = (unsigned short*)wsb;
    unsigned short* Bg = (unsigned short*)(wsb + WP_BYTES);
    float* P0 = (float*)(wsb + fixed);
    float* P1 = P0 + (size_t)NC * 2048;
    float* P2 = P1 + (size_t)NC * 2048;

    hipFuncSetAttribute(reinterpret_cast<const void*>(cg_mix3),
                        hipFuncAttributeMaxDynamicSharedMemorySize, 131072);
    hipFuncSetAttribute(reinterpret_cast<const void*>(cg_fiter<0>),
                        hipFuncAttributeMaxDynamicSharedMemorySize, 65536);
    hipFuncSetAttribute(reinterpret_cast<const void*>(cg_fiter<1>),
                        hipFuncAttributeMaxDynamicSharedMemorySize, 65536);

    cg_prep<<<320, 256, 0, stream>>>(mW, iW, Wp);
    cg_prepg<<<4, 256, 0, stream>>>(U, Bg);

    for (int base = 0; base < NSAMP; base += NC) {
        const int nc = (NSAMP - base < NC) ? (NSAMP - base) : NC;
        cg_mix3<<<nc / 16, 512, 131072, stream>>>(feats, (const bf16x8*)Wp, P0, P1, P2, base);
        // cur1 = P0 + mix(TP(P0,P1), iW0)  -> overwrite P1
        cg_fiter<0><<<nc / 16, 512, 65536, stream>>>(P0, P1, (const bf16x8*)Bg,
                                                     (const bf16x8*)Wp, P1, nullptr, base);
        // out  = P1 + mix(TP(P1,P2), iW1)
        cg_fiter<1><<<nc / 16, 512, 65536, stream>>>(P1, P2, (const bf16x8*)Bg,
                                                     (const bf16x8*)Wp, nullptr, out, base);
    }
}

// Round 12
// 106.323 us; speedup vs baseline: 7.7677x; 1.2502x over previous
//
#include <hip/hip_runtime.h>

#define NSAMP 4096
#define KCH   128
#define MDIM  7

typedef __attribute__((ext_vector_type(8))) short bf16x8;
typedef __attribute__((ext_vector_type(4))) float f32x4;
typedef __attribute__((ext_vector_type(4))) unsigned u32x4;

static constexpr int RB[4] = {0, 1, 4, 9};
static constexpr int RE[4] = {1, 4, 9, 16};
static constexpr int PR_L[16] = {0,1,1,1,2,2,2,2,2,3,3,3,3,3,3,3};
static constexpr int PR_M[16] = {0,0,1,2,0,1,2,3,4,0,1,2,3,4,5,6};

// path index by (L, l1, l2); -1 = no path  (Python enumeration order)
static constexpr int PIDX[4][4][4] = {
  { { 0,-1,-1,-1},{-1, 1,-1,-1},{-1,-1, 2,-1},{-1,-1,-1, 3} },
  { {-1, 4,-1,-1},{ 5, 6, 7,-1},{-1, 8, 9,10},{-1,-1,11,12} },
  { {-1,-1,13,-1},{-1,14,15,16},{17,18,19,20},{-1,21,22,23} },
  { {-1,-1,-1,24},{-1,-1,25,26},{-1,27,28,29},{30,31,32,33} }
};

// invalid (l,m) rows for zero-fill
static constexpr int ZL[12] = {0,0,0,0,0,0, 1,1,1,1, 2,2};
static constexpr int ZM[12] = {1,2,3,4,5,6, 3,4,5,6, 5,6};

#define WP_BYTES 1310720u   // 1280 sets * 512 shorts * 2B
#define BG_BYTES 16384u     // G matrix: 8 steps * 2(hi/lo) * 64 lanes * 8 bf16

static __device__ __forceinline__ unsigned short f2bf(float x) {
    unsigned u = __builtin_bit_cast(unsigned, x);
    u = u + 0x7FFFu + ((u >> 16) & 1u);
    return (unsigned short)(u >> 16);
}
static __device__ __forceinline__ float bf2f(unsigned short h) {
    unsigned u = ((unsigned)h) << 16;
    return __builtin_bit_cast(float, u);
}

// ---------------- K0: W -> bf16 hi/lo in B-fragment order ----------------
__global__ __launch_bounds__(256) void cg_prep(const float* __restrict__ mW,
                                               const float* __restrict__ iW,
                                               unsigned short* __restrict__ Wp)
{
    int gid = blockIdx.x * 256 + threadIdx.x;
    int lane = gid & 63;
    int set  = gid >> 6;                            // 1280 sets
    int spl = set & 1;
    int ks  = (set >> 1) & 3;
    int ct  = (set >> 3) & 7;
    int l   = (set >> 6) & 3;
    int mi  = set >> 8;                             // 0..4
    const float* src = (mi < 3) ? (mW + ((size_t)mi * 4 + l) * (KCH * KCH))
                                : (iW + ((size_t)(mi - 3) * 4 + l) * (KCH * KCH));
    int j  = ct * 16 + (lane & 15);
    int kb = ks * 32 + (lane >> 4) * 8;
    unsigned short o[8];
#pragma unroll
    for (int e = 0; e < 8; ++e) {
        float w = src[(size_t)(kb + e) * KCH + j];
        unsigned short h = f2bf(w);
        o[e] = spl ? f2bf(w - bf2f(h)) : h;
    }
    uint4 pk;
    unsigned* pw = (unsigned*)&pk;
#pragma unroll
    for (int q = 0; q < 4; ++q) pw[q] = (unsigned)o[2*q] | ((unsigned)o[2*q+1] << 16);
    *(uint4*)(Wp + (size_t)set * 512 + lane * 8) = pk;
}

// ---------------- K1: U -> G (pair-GEMM B operand) hi/lo in fragment order ----------------
__global__ __launch_bounds__(256) void cg_prepg(const float* __restrict__ U,
                                                unsigned short* __restrict__ Bg)
{
    const int gid  = blockIdx.x * 256 + threadIdx.x;   // 0..1023
    const int s    = gid >> 7;                         // k-step 0..7
    const int spl  = (gid >> 6) & 1;
    const int lane = gid & 63;
    const int c    = lane & 15;
    const int kb   = s * 32 + (lane >> 4) * 8;
    const int Lo   = PR_L[c], cm = PR_M[c];
    unsigned short o[8];
#pragma unroll
    for (int e = 0; e < 8; ++e) {
        const int k  = kb + e;
        const int i  = k >> 4, j = k & 15;
        const int l1 = PR_L[i], a = PR_M[i];
        const int l2 = PR_L[j], b = PR_M[j];
        const int p  = PIDX[Lo][l1][l2];
        float val = (p >= 0) ? U[p * 343 + (a * 7 + b) * 7 + cm] : 0.0f;
        unsigned short h = f2bf(val);
        o[e] = spl ? f2bf(val - bf2f(h)) : h;
    }
    uint4 pk;
    unsigned* pw = (unsigned*)&pk;
#pragma unroll
    for (int q = 0; q < 4; ++q) pw[q] = (unsigned)o[2*q] | ((unsigned)o[2*q+1] << 16);
    *(uint4*)(Bg + (size_t)((s * 2 + spl) * 64 + lane) * 8) = pk;
}

// A-fragment read from bf16 plane [256 rows][128], chunk-XOR swizzled by (key&7)
static __device__ __forceinline__ bf16x8 ldF(const unsigned short* P, int row16, int key, int c) {
    int cs = c ^ (key & 7);
    return *(const bf16x8*)(P + row16 * 128 + cs * 8);
}

// ---------------- K2: three mixer GEMMs, rows = samples (straight-line) ----------------
__global__ __launch_bounds__(512, 2) void cg_mix3(const float* __restrict__ feats,
                                                  const bf16x8* __restrict__ Wp,
                                                  float* __restrict__ P0,
                                                  float* __restrict__ P1,
                                                  float* __restrict__ P2,
                                                  int base)
{
    extern __shared__ char smem[];
    unsigned short* Fh = (unsigned short*)smem;            // 64 KB: [256 rows][128]
    unsigned short* Fl = Fh + 32768;                       // 64 KB

    const int tid  = threadIdx.x;
    const int lane = tid & 63;
    const int ct   = tid >> 6;              // wave id = j col-tile
    const int nl0  = blockIdx.x * 16;       // chunk-local sample base

    {
        const int row = tid >> 1;           // 0..255 = r*16 + nlr
        const int r   = row >> 4;
        const int nlr = row & 15;
        const int kh  = tid & 1;
        const int l = PR_L[r], m = PR_M[r];
        const float* g = feats + (((size_t)l * NSAMP + (base + nl0 + nlr)) * MDIM + m) * KCH + kh * 64;
        unsigned short* fh = Fh + row * 128;
        unsigned short* fl = Fl + row * 128;
#pragma unroll
        for (int c8 = 0; c8 < 8; ++c8) {
            f32x4 a = *(const f32x4*)(g + c8 * 8);
            f32x4 b = *(const f32x4*)(g + c8 * 8 + 4);
            float v[8] = {a[0], a[1], a[2], a[3], b[0], b[1], b[2], b[3]};
            unsigned short hi[8], lo[8];
#pragma unroll
            for (int i = 0; i < 8; ++i) {
                hi[i] = f2bf(v[i]);
                lo[i] = f2bf(v[i] - bf2f(hi[i]));
            }
            uint4 ph, pl;
            unsigned* pwh = (unsigned*)&ph;
            unsigned* pwl = (unsigned*)&pl;
#pragma unroll
            for (int q = 0; q < 4; ++q) {
                pwh[q] = (unsigned)hi[2*q] | ((unsigned)hi[2*q+1] << 16);
                pwl[q] = (unsigned)lo[2*q] | ((unsigned)lo[2*q+1] << 16);
            }
            const int cs = (kh * 8 + c8) ^ (nlr & 7);
            *(uint4*)(fh + cs * 8) = ph;
            *(uint4*)(fl + cs * 8) = pl;
        }
    }
    __syncthreads();

    const int kg = lane >> 4;
    const int l15 = lane & 15;
    const int j = ct * 16 + l15;

    // ---- dual sweep: mi = 0 and 1 ----
    f32x4 acc0[16], acc1[16];
#pragma unroll
    for (int r = 0; r < 16; ++r) {
        acc0[r][0]=acc0[r][1]=acc0[r][2]=acc0[r][3]=0.0f;
        acc1[r][0]=acc1[r][1]=acc1[r][2]=acc1[r][3]=0.0f;
    }
#pragma unroll
    for (int ks = 0; ks < 4; ++ks) {
#pragma unroll
        for (int l = 0; l < 4; ++l) {
            const int s0 = (((0 * 4 + l) * 8 + ct) * 4 + ks) * 2;
            const int s1 = (((1 * 4 + l) * 8 + ct) * 4 + ks) * 2;
            bf16x8 b0h = Wp[(size_t)s0 * 64 + lane];
            bf16x8 b0l = Wp[(size_t)(s0 + 1) * 64 + lane];
            bf16x8 b1h = Wp[(size_t)s1 * 64 + lane];
            bf16x8 b1l = Wp[(size_t)(s1 + 1) * 64 + lane];
#pragma unroll
            for (int r = RB[l]; r < RE[l]; ++r) {
                bf16x8 ah = ldF(Fh, r * 16 + l15, l15, ks * 4 + kg);
                bf16x8 al = ldF(Fl, r * 16 + l15, l15, ks * 4 + kg);
                acc0[r] = __builtin_amdgcn_mfma_f32_16x16x32_bf16(ah, b0h, acc0[r], 0, 0, 0);
                acc0[r] = __builtin_amdgcn_mfma_f32_16x16x32_bf16(ah, b0l, acc0[r], 0, 0, 0);
                acc0[r] = __builtin_amdgcn_mfma_f32_16x16x32_bf16(al, b0h, acc0[r], 0, 0, 0);
                acc1[r] = __builtin_amdgcn_mfma_f32_16x16x32_bf16(ah, b1h, acc1[r], 0, 0, 0);
                acc1[r] = __builtin_amdgcn_mfma_f32_16x16x32_bf16(ah, b1l, acc1[r], 0, 0, 0);
                acc1[r] = __builtin_amdgcn_mfma_f32_16x16x32_bf16(al, b1h, acc1[r], 0, 0, 0);
            }
        }
    }
#pragma unroll
    for (int r = 0; r < 16; ++r) {
#pragma unroll
        for (int q = 0; q < 4; ++q) {
            const int nl = nl0 + (lane >> 4) * 4 + q;
            P0[((size_t)nl * 16 + r) * KCH + j] = acc0[r][q];
            P1[((size_t)nl * 16 + r) * KCH + j] = acc1[r][q];
        }
    }

    // ---- single sweep: mi = 2 ----
#pragma unroll
    for (int r = 0; r < 16; ++r) { acc0[r][0]=acc0[r][1]=acc0[r][2]=acc0[r][3]=0.0f; }
#pragma unroll
    for (int ks = 0; ks < 4; ++ks) {
#pragma unroll
        for (int l = 0; l < 4; ++l) {
            const int s0 = (((2 * 4 + l) * 8 + ct) * 4 + ks) * 2;
            bf16x8 bh = Wp[(size_t)s0 * 64 + lane];
            bf16x8 bl = Wp[(size_t)(s0 + 1) * 64 + lane];
#pragma unroll
            for (int r = RB[l]; r < RE[l]; ++r) {
                bf16x8 ah = ldF(Fh, r * 16 + l15, l15, ks * 4 + kg);
                bf16x8 al = ldF(Fl, r * 16 + l15, l15, ks * 4 + kg);
                acc0[r] = __builtin_amdgcn_mfma_f32_16x16x32_bf16(ah, bh, acc0[r], 0, 0, 0);
                acc0[r] = __builtin_amdgcn_mfma_f32_16x16x32_bf16(ah, bl, acc0[r], 0, 0, 0);
                acc0[r] = __builtin_amdgcn_mfma_f32_16x16x32_bf16(al, bh, acc0[r], 0, 0, 0);
            }
        }
    }
#pragma unroll
    for (int r = 0; r < 16; ++r) {
#pragma unroll
        for (int q = 0; q < 4; ++q) {
            const int nl = nl0 + (lane >> 4) * 4 + q;
            P2[((size_t)nl * 16 + r) * KCH + j] = acc0[r][q];
        }
    }
}

// ---------------- K3: fused TP-GEMM + iter mix + residual (ILP-pipelined) ----------------
// Phase 1: 16 TP units per wave, depth-2 software pipeline; Bg hoisted to regs;
//          residual prefetched into racc before phase 1.
// Phase 2: iter MFMA sweep (2 MFMA vs W hi/lo), acc starts from racc.
template<int T>
__global__ __launch_bounds__(512, 2) void cg_fiter(const float* __restrict__ Pc,
                                                   const float* __restrict__ Pm,
                                                   const bf16x8* __restrict__ Bg,
                                                   const bf16x8* __restrict__ Wp,
                                                   float* __restrict__ Pout,
                                                   float* __restrict__ gout,
                                                   int base)
{
    extern __shared__ char smem[];
    unsigned short* Th = (unsigned short*)smem;   // 64 KB: [256 rows][128]

    const int tid  = threadIdx.x;
    const int lane = tid & 63;
    const int ct   = tid >> 6;            // wave id = channel col-tile
    const int nl0  = blockIdx.x * 16;

    const int kg  = lane >> 4;
    const int l15 = lane & 15;

    const int i0 = kg >> 1;
    const int j0 = (kg & 1) * 8;
    const int ch = ct * 16 + l15;         // A-row channel for loads
    const int c_out = l15;
    const int ch0   = ct * 16 + kg * 4;
    const int chunkA = ct * 2 + (kg >> 1);
    const int j = ct * 16 + l15;

    // ---- prefetch residual (used in phase 2; latency hides under phase 1) ----
    f32x4 racc[16];
#pragma unroll
    for (int r = 0; r < 16; ++r) {
#pragma unroll
        for (int q = 0; q < 4; ++q) {
            const int nl = kg * 4 + q;
            racc[r][q] = Pc[((size_t)(nl0 + nl) * 16 + r) * KCH + j];
        }
    }

    // ---- hoist Bg (G-matrix fragments) into registers ----
    bf16x8 bgh[8], bgl[8];
#pragma unroll
    for (int s = 0; s < 8; ++s) {
        bgh[s] = Bg[(size_t)(s * 2 + 0) * 64 + lane];
        bgl[s] = Bg[(size_t)(s * 2 + 1) * 64 + lane];
    }

    auto load_unit = [&](int u, float (&cv)[8], float (&mv)[8]) {
        const float* pc = Pc + ((size_t)(nl0 + u) * 16) * KCH + ch;
        const float* pm = Pm + ((size_t)(nl0 + u) * 16) * KCH + ch;
#pragma unroll
        for (int e = 0; e < 8; ++e) {
            cv[e] = pc[(size_t)(i0 + 2 * e) * KCH];
            mv[e] = pm[(size_t)(j0 + e) * KCH];
        }
    };

    auto do_unit = [&](int u, const float (&cv)[8], const float (&mv)[8]) {
        f32x4 acc = {0.0f, 0.0f, 0.0f, 0.0f};
#pragma unroll
        for (int s = 0; s < 8; ++s) {
            float pf[8];
#pragma unroll
            for (int e = 0; e < 8; ++e) pf[e] = cv[s] * mv[e];
            unsigned ah[4];
#pragma unroll
            for (int d = 0; d < 4; ++d) {
                asm("v_cvt_pk_bf16_f32 %0, %1, %2" : "=v"(ah[d]) : "v"(pf[2*d]), "v"(pf[2*d+1]));
            }
            const u32x4 AH = {ah[0], ah[1], ah[2], ah[3]};
            const bf16x8 a_h = __builtin_bit_cast(bf16x8, AH);
            acc = __builtin_amdgcn_mfma_f32_16x16x32_bf16(a_h, bgh[s], acc, 0, 0, 0);
            acc = __builtin_amdgcn_mfma_f32_16x16x32_bf16(a_h, bgl[s], acc, 0, 0, 0);
        }
        // write acc (4 channels of c-row c_out, sample u) as bf16 to LDS
        const int row16 = u * 16 + c_out;
        const int key   = (u ^ c_out) & 7;
        const int cs    = chunkA ^ key;
        const int soff  = row16 * 128 + cs * 8 + (ch0 & 7);
        const unsigned short h0 = f2bf(acc[0]);
        const unsigned short h1 = f2bf(acc[1]);
        const unsigned short h2 = f2bf(acc[2]);
        const unsigned short h3 = f2bf(acc[3]);
        *(unsigned*)(Th + soff)     = (unsigned)h0 | ((unsigned)h1 << 16);
        *(unsigned*)(Th + soff + 2) = (unsigned)h2 | ((unsigned)h3 << 16);
    };

    // ---- phase 1: depth-2 software pipeline over 16 units ----
    float cvA[8], mvA[8], cvB[8], mvB[8];
    load_unit(0, cvA, mvA);
#pragma unroll 1
    for (int uu = 0; uu < 8; ++uu) {
        load_unit(2 * uu + 1, cvB, mvB);
        do_unit(2 * uu, cvA, mvA);
        if (uu < 7) load_unit(2 * uu + 2, cvA, mvA);
        do_unit(2 * uu + 1, cvB, mvB);
    }
    __syncthreads();

    // ---- phase 2: iter MFMA sweep, acc = prefetched residual ----
    f32x4 acc[16];
#pragma unroll
    for (int r = 0; r < 16; ++r) acc[r] = racc[r];

#pragma unroll
    for (int ks = 0; ks < 4; ++ks) {
#pragma unroll
        for (int l = 0; l < 4; ++l) {
            const int s0 = ((((3 + T) * 4 + l) * 8 + ct) * 4 + ks) * 2;
            bf16x8 bh = Wp[(size_t)s0 * 64 + lane];
            bf16x8 bl = Wp[(size_t)(s0 + 1) * 64 + lane];
#pragma unroll
            for (int r = RB[l]; r < RE[l]; ++r) {
                // row = sample*16 + c-row; key = sample ^ c-row
                bf16x8 ah = ldF(Th, l15 * 16 + r, l15 ^ r, ks * 4 + kg);
                acc[r] = __builtin_amdgcn_mfma_f32_16x16x32_bf16(ah, bh, acc[r], 0, 0, 0);
                acc[r] = __builtin_amdgcn_mfma_f32_16x16x32_bf16(ah, bl, acc[r], 0, 0, 0);
            }
        }
    }

#pragma unroll
    for (int r = 0; r < 16; ++r) {
#pragma unroll
        for (int q = 0; q < 4; ++q) {
            const int nl = nl0 + kg * 4 + q;
            const float val = acc[r][q];
            if (T == 0) {
                Pout[((size_t)nl * 16 + r) * KCH + j] = val;
            } else {
                const int n = base + nl;
                gout[(((size_t)PR_L[r] * NSAMP + n) * MDIM + PR_M[r]) * KCH + j] = val;
            }
        }
    }

    if (T == 1) {
        // zero-fill the 12 invalid (l,m) rows
        const int j2 = tid & 127;
        const int g  = tid >> 7;     // 0..3
#pragma unroll
        for (int z = 0; z < 12; ++z) {
#pragma unroll
            for (int i = 0; i < 4; ++i) {
                const int n = base + nl0 + g * 4 + i;
                gout[(((size_t)ZL[z] * NSAMP + n) * MDIM + ZM[z]) * KCH + j2] = 0.0f;
            }
        }
    }
}

extern "C" void kernel_launch(void* const* d_in, const int* in_sizes, int n_in,
                              void* d_out, int out_size, void* d_ws, size_t ws_size,
                              hipStream_t stream)
{
    const float* feats = (const float*)d_in[0];
    const float* U     = (const float*)d_in[1];
    const float* mW    = (const float*)d_in[2];
    const float* iW    = (const float*)d_in[3];
    float* out = (float*)d_out;

    const size_t fixed = (size_t)WP_BYTES + BG_BYTES;
    size_t avail = (ws_size > fixed) ? (ws_size - fixed) : 0;
    int NC = (int)(avail / 24576);            // per-sample: P0,P1,P2 = 3*8192 B
    NC = (NC / 16) * 16;
    if (NC > NSAMP) NC = NSAMP;
    if (NC < 16) return;

    char* wsb = (char*)d_ws;
    unsigned short* Wp = (unsigned short*)wsb;
    unsigned short* Bg = (unsigned short*)(wsb + WP_BYTES);
    float* P0 = (float*)(wsb + fixed);
    float* P1 = P0 + (size_t)NC * 2048;
    float* P2 = P1 + (size_t)NC * 2048;

    hipFuncSetAttribute(reinterpret_cast<const void*>(cg_mix3),
                        hipFuncAttributeMaxDynamicSharedMemorySize, 131072);
    hipFuncSetAttribute(reinterpret_cast<const void*>(cg_fiter<0>),
                        hipFuncAttributeMaxDynamicSharedMemorySize, 65536);
    hipFuncSetAttribute(reinterpret_cast<const void*>(cg_fiter<1>),
                        hipFuncAttributeMaxDynamicSharedMemorySize, 65536);

    cg_prep<<<320, 256, 0, stream>>>(mW, iW, Wp);
    cg_prepg<<<4, 256, 0, stream>>>(U, Bg);

    for (int base = 0; base < NSAMP; base += NC) {
        const int nc = (NSAMP - base < NC) ? (NSAMP - base) : NC;
        cg_mix3<<<nc / 16, 512, 131072, stream>>>(feats, (const bf16x8*)Wp, P0, P1, P2, base);
        // cur1 = P0 + mix(TP(P0,P1), iW0)  -> overwrite P1
        cg_fiter<0><<<nc / 16, 512, 65536, stream>>>(P0, P1, (const bf16x8*)Bg,
                                                     (const bf16x8*)Wp, P1, nullptr, base);
        // out  = P1 + mix(TP(P1,P2), iW1)
        cg_fiter<1><<<nc / 16, 512, 65536, stream>>>(P1, P2, (const bf16x8*)Bg,
                                                     (const bf16x8*)Wp, nullptr, out, base);
    }
}

// Round 13
// 106.098 us; speedup vs baseline: 7.7842x; 1.0021x over previous
//
#include <hip/hip_runtime.h>

#define NSAMP 4096
#define KCH   128
#define MDIM  7

typedef __attribute__((ext_vector_type(8))) short bf16x8;
typedef __attribute__((ext_vector_type(4))) float f32x4;
typedef __attribute__((ext_vector_type(4))) unsigned u32x4;

static constexpr int RB[4] = {0, 1, 4, 9};
static constexpr int RE[4] = {1, 4, 9, 16};
static constexpr int PR_L[16] = {0,1,1,1,2,2,2,2,2,3,3,3,3,3,3,3};
static constexpr int PR_M[16] = {0,0,1,2,0,1,2,3,4,0,1,2,3,4,5,6};

// path index by (L, l1, l2); -1 = no path  (Python enumeration order)
static constexpr int PIDX[4][4][4] = {
  { { 0,-1,-1,-1},{-1, 1,-1,-1},{-1,-1, 2,-1},{-1,-1,-1, 3} },
  { {-1, 4,-1,-1},{ 5, 6, 7,-1},{-1, 8, 9,10},{-1,-1,11,12} },
  { {-1,-1,13,-1},{-1,14,15,16},{17,18,19,20},{-1,21,22,23} },
  { {-1,-1,-1,24},{-1,-1,25,26},{-1,27,28,29},{30,31,32,33} }
};

// invalid (l,m) rows for zero-fill
static constexpr int ZL[12] = {0,0,0,0,0,0, 1,1,1,1, 2,2};
static constexpr int ZM[12] = {1,2,3,4,5,6, 3,4,5,6, 5,6};

#define WP_BYTES 1310720u   // 1280 sets * 512 shorts * 2B
#define BG_BYTES 16384u     // G matrix: 8 steps * 2(hi/lo) * 64 lanes * 8 bf16

static __device__ __forceinline__ unsigned short f2bf(float x) {
    unsigned u = __builtin_bit_cast(unsigned, x);
    u = u + 0x7FFFu + ((u >> 16) & 1u);
    return (unsigned short)(u >> 16);
}
static __device__ __forceinline__ float bf2f(unsigned short h) {
    unsigned u = ((unsigned)h) << 16;
    return __builtin_bit_cast(float, u);
}

// ---------------- K0: W -> bf16 hi/lo in B-fragment order ----------------
__global__ __launch_bounds__(256) void cg_prep(const float* __restrict__ mW,
                                               const float* __restrict__ iW,
                                               unsigned short* __restrict__ Wp)
{
    int gid = blockIdx.x * 256 + threadIdx.x;
    int lane = gid & 63;
    int set  = gid >> 6;                            // 1280 sets
    int spl = set & 1;
    int ks  = (set >> 1) & 3;
    int ct  = (set >> 3) & 7;
    int l   = (set >> 6) & 3;
    int mi  = set >> 8;                             // 0..4
    const float* src = (mi < 3) ? (mW + ((size_t)mi * 4 + l) * (KCH * KCH))
                                : (iW + ((size_t)(mi - 3) * 4 + l) * (KCH * KCH));
    int j  = ct * 16 + (lane & 15);
    int kb = ks * 32 + (lane >> 4) * 8;
    unsigned short o[8];
#pragma unroll
    for (int e = 0; e < 8; ++e) {
        float w = src[(size_t)(kb + e) * KCH + j];
        unsigned short h = f2bf(w);
        o[e] = spl ? f2bf(w - bf2f(h)) : h;
    }
    uint4 pk;
    unsigned* pw = (unsigned*)&pk;
#pragma unroll
    for (int q = 0; q < 4; ++q) pw[q] = (unsigned)o[2*q] | ((unsigned)o[2*q+1] << 16);
    *(uint4*)(Wp + (size_t)set * 512 + lane * 8) = pk;
}

// ---------------- K1: U -> G (pair-GEMM B operand) hi/lo in fragment order ----------------
__global__ __launch_bounds__(256) void cg_prepg(const float* __restrict__ U,
                                                unsigned short* __restrict__ Bg)
{
    const int gid  = blockIdx.x * 256 + threadIdx.x;   // 0..1023
    const int s    = gid >> 7;                         // k-step 0..7
    const int spl  = (gid >> 6) & 1;
    const int lane = gid & 63;
    const int c    = lane & 15;
    const int kb   = s * 32 + (lane >> 4) * 8;
    const int Lo   = PR_L[c], cm = PR_M[c];
    unsigned short o[8];
#pragma unroll
    for (int e = 0; e < 8; ++e) {
        const int k  = kb + e;
        const int i  = k >> 4, j = k & 15;
        const int l1 = PR_L[i], a = PR_M[i];
        const int l2 = PR_L[j], b = PR_M[j];
        const int p  = PIDX[Lo][l1][l2];
        float val = (p >= 0) ? U[p * 343 + (a * 7 + b) * 7 + cm] : 0.0f;
        unsigned short h = f2bf(val);
        o[e] = spl ? f2bf(val - bf2f(h)) : h;
    }
    uint4 pk;
    unsigned* pw = (unsigned*)&pk;
#pragma unroll
    for (int q = 0; q < 4; ++q) pw[q] = (unsigned)o[2*q] | ((unsigned)o[2*q+1] << 16);
    *(uint4*)(Bg + (size_t)((s * 2 + spl) * 64 + lane) * 8) = pk;
}

// A-fragment read from bf16 plane [256 rows][128], chunk-XOR swizzled by (key&7)
static __device__ __forceinline__ bf16x8 ldF(const unsigned short* P, int row16, int key, int c) {
    int cs = c ^ (key & 7);
    return *(const bf16x8*)(P + row16 * 128 + cs * 8);
}

// ---- stage feats -> hi/lo bf16 LDS (rows r*16+sample, chunk-XOR by sample&7) ----
static __device__ __forceinline__ void stage_feats(const float* __restrict__ feats,
                                                   unsigned short* Fh, unsigned short* Fl,
                                                   int tid, int n0)
{
    const int row = tid >> 1;           // 0..255 = r*16 + nlr
    const int r   = row >> 4;
    const int nlr = row & 15;
    const int kh  = tid & 1;
    const int l = PR_L[r], m = PR_M[r];
    const float* g = feats + (((size_t)l * NSAMP + (n0 + nlr)) * MDIM + m) * KCH + kh * 64;
    unsigned short* fh = Fh + row * 128;
    unsigned short* fl = Fl + row * 128;
#pragma unroll
    for (int c8 = 0; c8 < 8; ++c8) {
        f32x4 a = *(const f32x4*)(g + c8 * 8);
        f32x4 b = *(const f32x4*)(g + c8 * 8 + 4);
        float v[8] = {a[0], a[1], a[2], a[3], b[0], b[1], b[2], b[3]};
        unsigned short hi[8], lo[8];
#pragma unroll
        for (int i = 0; i < 8; ++i) {
            hi[i] = f2bf(v[i]);
            lo[i] = f2bf(v[i] - bf2f(hi[i]));
        }
        uint4 ph, pl;
        unsigned* pwh = (unsigned*)&ph;
        unsigned* pwl = (unsigned*)&pl;
#pragma unroll
        for (int q = 0; q < 4; ++q) {
            pwh[q] = (unsigned)hi[2*q] | ((unsigned)hi[2*q+1] << 16);
            pwl[q] = (unsigned)lo[2*q] | ((unsigned)lo[2*q+1] << 16);
        }
        const int cs = (kh * 8 + c8) ^ (nlr & 7);
        *(uint4*)(fh + cs * 8) = ph;
        *(uint4*)(fl + cs * 8) = pl;
    }
}

// ---- one mixer sweep (3-MFMA hi/lo), feats layout rows r*16+sample ----
static __device__ __forceinline__ void mix_sweep(const unsigned short* Fh, const unsigned short* Fl,
                                                 const bf16x8* __restrict__ Wp, int mi,
                                                 int ct, int lane, f32x4 (&acc)[16])
{
    const int kg = lane >> 4;
    const int l15 = lane & 15;
#pragma unroll
    for (int r = 0; r < 16; ++r) { acc[r][0]=acc[r][1]=acc[r][2]=acc[r][3]=0.0f; }
#pragma unroll
    for (int ks = 0; ks < 4; ++ks) {
#pragma unroll
        for (int l = 0; l < 4; ++l) {
            const int s0 = (((mi * 4 + l) * 8 + ct) * 4 + ks) * 2;
            bf16x8 bh = Wp[(size_t)s0 * 64 + lane];
            bf16x8 bl = Wp[(size_t)(s0 + 1) * 64 + lane];
#pragma unroll
            for (int r = RB[l]; r < RE[l]; ++r) {
                bf16x8 ah = ldF(Fh, r * 16 + l15, l15, ks * 4 + kg);
                bf16x8 al = ldF(Fl, r * 16 + l15, l15, ks * 4 + kg);
                acc[r] = __builtin_amdgcn_mfma_f32_16x16x32_bf16(ah, bh, acc[r], 0, 0, 0);
                acc[r] = __builtin_amdgcn_mfma_f32_16x16x32_bf16(ah, bl, acc[r], 0, 0, 0);
                acc[r] = __builtin_amdgcn_mfma_f32_16x16x32_bf16(al, bh, acc[r], 0, 0, 0);
            }
        }
    }
}

// ---- write a C-layout accumulator into a bf16 LDS plane (rows sample*16+r, key=sample&7) ----
static __device__ __forceinline__ void acc_to_lds(const f32x4 (&acc)[16], unsigned short* P,
                                                  int ct, int lane)
{
    const int kg = lane >> 4;
    const int l15 = lane & 15;
    const int chnk = ct * 2 + (l15 >> 3);
#pragma unroll
    for (int r = 0; r < 16; ++r) {
#pragma unroll
        for (int q = 0; q < 4; ++q) {
            const int smp = kg * 4 + q;
            const int cs = chnk ^ (smp & 7);
            P[(smp * 16 + r) * 128 + cs * 8 + (l15 & 7)] = f2bf(acc[r][q]);
        }
    }
}

// ---- TP (pair-GEMM) + in-place tp overwrite + iter sweep; shared by fuseA/fuseB ----
// Ch: cur bf16 plane (overwritten group-wise with tp), Mt: mt bf16 plane.
// racc: residual in/out (becomes the iter result).
static __device__ __forceinline__ void tp_iter(unsigned short* Ch, const unsigned short* Mt,
                                               const bf16x8* __restrict__ Bg,
                                               const bf16x8* __restrict__ Wp, int miW,
                                               int ct, int lane, f32x4 (&racc)[16])
{
    const int kg  = lane >> 4;
    const int l15 = lane & 15;
    const int i0 = kg >> 1;
    const int j0 = (kg & 1) * 8;
    const int chnk = ct * 2 + (l15 >> 3);   // chunk of my load channel
    const int chA  = ct * 2 + (kg >> 1);    // chunk of my output channels ch0..ch0+3
    const int co4  = (kg * 4) & 7;

    bf16x8 bgh[8], bgl[8];
#pragma unroll
    for (int s = 0; s < 8; ++s) {
        bgh[s] = Bg[(size_t)(s * 2 + 0) * 64 + lane];
        bgl[s] = Bg[(size_t)(s * 2 + 1) * 64 + lane];
    }

    f32x4 tpa[4];
#pragma unroll 1
    for (int g = 0; g < 4; ++g) {
#pragma unroll
        for (int uu = 0; uu < 4; ++uu) {
            const int u = g * 4 + uu;
            const int cs = chnk ^ (u & 7);
            const unsigned short* cb = Ch + u * 2048 + cs * 8 + (l15 & 7);
            const unsigned short* mb = Mt + u * 2048 + cs * 8 + (l15 & 7);
            float cvv[8], mvv[8];
#pragma unroll
            for (int s = 0; s < 8; ++s) cvv[s] = bf2f(cb[(i0 + 2 * s) * 128]);
#pragma unroll
            for (int e = 0; e < 8; ++e) mvv[e] = bf2f(mb[(j0 + e) * 128]);
            f32x4 acc = {0.0f, 0.0f, 0.0f, 0.0f};
#pragma unroll
            for (int s = 0; s < 8; ++s) {
                float pf[8];
#pragma unroll
                for (int e = 0; e < 8; ++e) pf[e] = cvv[s] * mvv[e];
                unsigned ah[4];
#pragma unroll
                for (int d = 0; d < 4; ++d) {
                    asm("v_cvt_pk_bf16_f32 %0, %1, %2" : "=v"(ah[d]) : "v"(pf[2*d]), "v"(pf[2*d+1]));
                }
                const u32x4 AH = {ah[0], ah[1], ah[2], ah[3]};
                const bf16x8 a_h = __builtin_bit_cast(bf16x8, AH);
                acc = __builtin_amdgcn_mfma_f32_16x16x32_bf16(a_h, bgh[s], acc, 0, 0, 0);
                acc = __builtin_amdgcn_mfma_f32_16x16x32_bf16(a_h, bgl[s], acc, 0, 0, 0);
            }
            tpa[uu] = acc;
        }
        __syncthreads();   // all reads of this group's cur slots done
#pragma unroll
        for (int uu = 0; uu < 4; ++uu) {
            const int u = g * 4 + uu;
            const int cs = chA ^ (u & 7);
            const int soff = (u * 16 + l15) * 128 + cs * 8 + co4;
            const unsigned short h0 = f2bf(tpa[uu][0]);
            const unsigned short h1 = f2bf(tpa[uu][1]);
            const unsigned short h2 = f2bf(tpa[uu][2]);
            const unsigned short h3 = f2bf(tpa[uu][3]);
            *(unsigned*)(Ch + soff)     = (unsigned)h0 | ((unsigned)h1 << 16);
            *(unsigned*)(Ch + soff + 2) = (unsigned)h2 | ((unsigned)h3 << 16);
        }
    }
    __syncthreads();   // all tp written

    // iter sweep: A = tp plane (rows sample*16 + c-row, key=sample&7), B = W[miW]
#pragma unroll
    for (int ks = 0; ks < 4; ++ks) {
#pragma unroll
        for (int l = 0; l < 4; ++l) {
            const int s0 = (((miW * 4 + l) * 8 + ct) * 4 + ks) * 2;
            bf16x8 bh = Wp[(size_t)s0 * 64 + lane];
            bf16x8 bl = Wp[(size_t)(s0 + 1) * 64 + lane];
#pragma unroll
            for (int r = RB[l]; r < RE[l]; ++r) {
                bf16x8 ah = ldF(Ch, l15 * 16 + r, l15, ks * 4 + kg);
                racc[r] = __builtin_amdgcn_mfma_f32_16x16x32_bf16(ah, bh, racc[r], 0, 0, 0);
                racc[r] = __builtin_amdgcn_mfma_f32_16x16x32_bf16(ah, bl, racc[r], 0, 0, 0);
            }
        }
    }
}

// ---------------- fuseA: mix0 + mix1 + TP + iter0 -> cur1 (f32) ----------------
__global__ __launch_bounds__(512, 2) void cg_fuseA(const float* __restrict__ feats,
                                                   const bf16x8* __restrict__ Wp,
                                                   const bf16x8* __restrict__ Bg,
                                                   float* __restrict__ Pcur,
                                                   int base)
{
    extern __shared__ char smem[];
    unsigned short* Fh = (unsigned short*)smem;   // 64 KB; later = cur/tp plane
    unsigned short* Fl = Fh + 32768;              // 64 KB; later = mt plane

    const int tid  = threadIdx.x;
    const int lane = tid & 63;
    const int ct   = tid >> 6;
    const int nl0  = blockIdx.x * 16;
    const int kg   = lane >> 4;
    const int l15  = lane & 15;
    const int j    = ct * 16 + l15;

    stage_feats(feats, Fh, Fl, tid, base + nl0);
    __syncthreads();

    f32x4 acc0[16], acc1[16];
    mix_sweep(Fh, Fl, Wp, 0, ct, lane, acc0);   // cur0
    mix_sweep(Fh, Fl, Wp, 1, ct, lane, acc1);   // mt1
    __syncthreads();                            // all feats reads done

    acc_to_lds(acc0, Fh, ct, lane);             // cur bf16 (also kept in regs as residual)
    acc_to_lds(acc1, Fl, ct, lane);             // mt bf16
    __syncthreads();

    tp_iter(Fh, Fl, Bg, Wp, 3, ct, lane, acc0); // acc0 += mix(tp, iW0) -> cur1

#pragma unroll
    for (int r = 0; r < 16; ++r) {
#pragma unroll
        for (int q = 0; q < 4; ++q) {
            const int nl = nl0 + kg * 4 + q;
            Pcur[((size_t)nl * 16 + r) * KCH + j] = acc0[r][q];
        }
    }
}

// ---------------- fuseB: mix2 + TP + iter1 -> out ----------------
__global__ __launch_bounds__(512, 2) void cg_fuseB(const float* __restrict__ feats,
                                                   const bf16x8* __restrict__ Wp,
                                                   const bf16x8* __restrict__ Bg,
                                                   const float* __restrict__ Pcur,
                                                   float* __restrict__ gout,
                                                   int base)
{
    extern __shared__ char smem[];
    unsigned short* Fh = (unsigned short*)smem;   // 64 KB; later = cur/tp plane
    unsigned short* Fl = Fh + 32768;              // 64 KB; later = mt plane

    const int tid  = threadIdx.x;
    const int lane = tid & 63;
    const int ct   = tid >> 6;
    const int nl0  = blockIdx.x * 16;
    const int kg   = lane >> 4;
    const int l15  = lane & 15;
    const int j    = ct * 16 + l15;

    // prefetch residual cur1 (latency hides under staging + mix)
    f32x4 racc[16];
#pragma unroll
    for (int r = 0; r < 16; ++r) {
#pragma unroll
        for (int q = 0; q < 4; ++q) {
            const int nl = nl0 + kg * 4 + q;
            racc[r][q] = Pcur[((size_t)nl * 16 + r) * KCH + j];
        }
    }

    stage_feats(feats, Fh, Fl, tid, base + nl0);
    __syncthreads();

    f32x4 accm[16];
    mix_sweep(Fh, Fl, Wp, 2, ct, lane, accm);   // mt2
    __syncthreads();                            // all feats reads done

    acc_to_lds(racc, Fh, ct, lane);             // cur1 bf16
    acc_to_lds(accm, Fl, ct, lane);             // mt2 bf16
    __syncthreads();

    tp_iter(Fh, Fl, Bg, Wp, 4, ct, lane, racc); // racc += mix(tp, iW1) -> final

#pragma unroll
    for (int r = 0; r < 16; ++r) {
#pragma unroll
        for (int q = 0; q < 4; ++q) {
            const int n = base + nl0 + kg * 4 + q;
            gout[(((size_t)PR_L[r] * NSAMP + n) * MDIM + PR_M[r]) * KCH + j] = racc[r][q];
        }
    }

    // zero-fill the 12 invalid (l,m) rows
    {
        const int j2 = tid & 127;
        const int g  = tid >> 7;     // 0..3
#pragma unroll
        for (int z = 0; z < 12; ++z) {
#pragma unroll
            for (int i = 0; i < 4; ++i) {
                const int n = base + nl0 + g * 4 + i;
                gout[(((size_t)ZL[z] * NSAMP + n) * MDIM + ZM[z]) * KCH + j2] = 0.0f;
            }
        }
    }
}

extern "C" void kernel_launch(void* const* d_in, const int* in_sizes, int n_in,
                              void* d_out, int out_size, void* d_ws, size_t ws_size,
                              hipStream_t stream)
{
    const float* feats = (const float*)d_in[0];
    const float* U     = (const float*)d_in[1];
    const float* mW    = (const float*)d_in[2];
    const float* iW    = (const float*)d_in[3];
    float* out = (float*)d_out;

    const size_t fixed = (size_t)WP_BYTES + BG_BYTES;
    size_t avail = (ws_size > fixed) ? (ws_size - fixed) : 0;
    int NC = (int)(avail / 8192);             // per-sample: Pcur = 16*128*4 B
    NC = (NC / 16) * 16;
    if (NC > NSAMP) NC = NSAMP;
    if (NC < 16) return;

    char* wsb = (char*)d_ws;
    unsigned short* Wp = (unsigned short*)wsb;
    unsigned short* Bg = (unsigned short*)(wsb + WP_BYTES);
    float* Pcur = (float*)(wsb + fixed);

    hipFuncSetAttribute(reinterpret_cast<const void*>(cg_fuseA),
                        hipFuncAttributeMaxDynamicSharedMemorySize, 131072);
    hipFuncSetAttribute(reinterpret_cast<const void*>(cg_fuseB),
                        hipFuncAttributeMaxDynamicSharedMemorySize, 131072);

    cg_prep<<<320, 256, 0, stream>>>(mW, iW, Wp);
    cg_prepg<<<4, 256, 0, stream>>>(U, Bg);

    for (int base = 0; base < NSAMP; base += NC) {
        const int nc = (NSAMP - base < NC) ? (NSAMP - base) : NC;
        cg_fuseA<<<nc / 16, 512, 131072, stream>>>(feats, (const bf16x8*)Wp,
                                                   (const bf16x8*)Bg, Pcur, base);
        cg_fuseB<<<nc / 16, 512, 131072, stream>>>(feats, (const bf16x8*)Wp,
                                                   (const bf16x8*)Bg, Pcur, out, base);
    }
}